// Round 15
// baseline (463.083 us; speedup 1.0000x reference)
//
#include <hip/hip_runtime.h>
#include <math.h>

#define B_   2
#define T_   2048
#define DIM_ 2048
#define H_   16

typedef __attribute__((ext_vector_type(8))) _Float16 half8;
typedef __attribute__((ext_vector_type(4))) float f32x4;

__device__ __forceinline__ float sigmoidf_(float x) { return 1.0f / (1.0f + __expf(-x)); }

__device__ __forceinline__ void gload16(const _Float16* g, _Float16* l) {
    __builtin_amdgcn_global_load_lds((const __attribute__((address_space(1))) void*)g,
                                     (__attribute__((address_space(3))) void*)l, 16, 0, 0);
}

#define VMW(n) asm volatile("s_waitcnt vmcnt(" #n ")" ::: "memory")

// Swizzled transpose-LDS addressing for [row][72] f16 tiles holding [row][s].
__device__ __forceinline__ int tsw(int row, int s) {
    return row * 72 + ((((s >> 3) ^ ((row >> 3) & 7)) << 3) | (s & 7));
}
__device__ __forceinline__ int tswb(int row, int sb) {
    return row * 72 + (((sb ^ ((row >> 3) & 7)) << 3));
}

// Depthwise causal conv K=4, 8 channels, fp32 math.
__device__ __forceinline__ void conv8(const _Float16* __restrict__ src,
                                      const float* __restrict__ w,
                                      const float* __restrict__ bias,
                                      size_t rb, int t, int ch, float* acc)
{
    float4 w4[8];
#pragma unroll
    for (int u = 0; u < 8; ++u) {
        w4[u] = *(const float4*)(w + (ch + u) * 4);
        acc[u] = bias[ch + u];
    }
#pragma unroll
    for (int j = 0; j < 4; ++j) {
        if (t - 3 + j >= 0) {
            half8 xv = *(const half8*)(src + rb + (ptrdiff_t)(j - 3) * DIM_);
#pragma unroll
            for (int u = 0; u < 8; ++u)
                acc[u] += (float)xv[u] * ((const float*)&w4[u])[j];
        }
    }
}

// ---------------------------------------------------------------------------
// prep: z<5 -> weight transpose W[K][N] f32 -> Wt[N][K] f16 (vectorized);
//       z==5 -> x f32->f16 cvt.
// ---------------------------------------------------------------------------
__global__ __launch_bounds__(256) void prep(const float* __restrict__ W0,
                                            const float* __restrict__ W1,
                                            const float* __restrict__ W2,
                                            const float* __restrict__ W3,
                                            const float* __restrict__ W4,
                                            _Float16* __restrict__ wbase,
                                            const float* __restrict__ x,
                                            _Float16* __restrict__ xh)
{
    const int z = blockIdx.z;
    if (z == 5) {
        size_t blk = ((size_t)blockIdx.y * 32 + blockIdx.x) * 8192;
#pragma unroll
        for (int j = 0; j < 4; ++j) {
            size_t i = blk + (size_t)j * 2048 + (size_t)threadIdx.x * 8;
            float4 a = *(const float4*)(x + i);
            float4 b = *(const float4*)(x + i + 4);
            half8 h;
            h[0] = (_Float16)a.x; h[1] = (_Float16)a.y; h[2] = (_Float16)a.z; h[3] = (_Float16)a.w;
            h[4] = (_Float16)b.x; h[5] = (_Float16)b.y; h[6] = (_Float16)b.z; h[7] = (_Float16)b.w;
            *(half8*)(xh + i) = h;
        }
        return;
    }
    __shared__ float t[64 * 65];
    const float* W = z == 0 ? W0 : z == 1 ? W1 : z == 2 ? W2 : z == 3 ? W3 : W4;
    _Float16* Wt = wbase + (size_t)z * DIM_ * DIM_;
    const int n0 = blockIdx.x * 64, k0 = blockIdx.y * 64;
#pragma unroll
    for (int rep = 0; rep < 4; ++rep) {
        int row = rep * 16 + (threadIdx.x >> 4);
        int qc = threadIdx.x & 15;
        float4 v = *(const float4*)(W + (size_t)(k0 + row) * DIM_ + n0 + qc * 4);
        t[row * 65 + qc * 4 + 0] = v.x;
        t[row * 65 + qc * 4 + 1] = v.y;
        t[row * 65 + qc * 4 + 2] = v.z;
        t[row * 65 + qc * 4 + 3] = v.w;
    }
    __syncthreads();
#pragma unroll
    for (int rep = 0; rep < 2; ++rep) {
        int r = rep * 32 + (threadIdx.x >> 3);
        int q = threadIdx.x & 7;
        half8 o;
#pragma unroll
        for (int j = 0; j < 8; ++j)
            o[j] = (_Float16)t[(q * 8 + j) * 65 + r];
        *(half8*)(Wt + (size_t)(n0 + r) * DIM_ + k0 + q * 8) = o;
    }
}

// ---------------------------------------------------------------------------
// 8-phase pipelined MFMA GEMM (measured-best on proj): 256x256 tile, BK=64,
// 2 K-tiles/iter, 8 waves (2M x 4N), counted vmcnt(4), 3-bit XOR swizzle.
// Epilogue: two-pass LDS bounce -> coalesced half8 stores.
// ---------------------------------------------------------------------------
template <int BM>
__global__ __launch_bounds__(512, 1) void gemm8ph(const _Float16* __restrict__ A,
                                                  const _Float16* __restrict__ Bt,
                                                  _Float16* __restrict__ C0, _Float16* __restrict__ C1,
                                                  _Float16* __restrict__ C2, _Float16* __restrict__ C3,
                                                  int K, int nx, int cpx)
{
    constexpr int MF  = BM / 32;
    constexpr int AQ  = MF / 4;
    constexpr int ASZ = BM * 64;
    constexpr int DSZ = (BM + 256) * 64;
    __shared__ _Float16 lds[2 * DSZ];

    const int tid = threadIdx.x;
    const int lane = tid & 63, w = tid >> 6;
    const int wr = w >> 2, wc = w & 3;
    const int l15 = lane & 15, l16 = lane >> 4;

    const int bid = blockIdx.x;
    const int swz = (bid & 7) * cpx + (bid >> 3);
    const int bm = (swz / nx) * BM, bn = (swz % nx) * 256;

    const int r0 = tid >> 3;
    const int c0 = ((tid & 7) ^ (r0 & 7)) * 8;
    const _Float16* Ab = A + (size_t)(bm + r0) * K + c0;
    const _Float16* Bb = Bt + (size_t)(bn + r0) * K + c0;

#define STAGE_A(d, kt) do { _Pragma("unroll")                                    \
    for (int u = 0; u < BM / 64; ++u)                                            \
        gload16(Ab + (size_t)(u * 64) * K + (size_t)(kt) * 64,                   \
                lds + (d) * DSZ + u * 4096 + tid * 8); } while (0)
#define STAGE_B(d, h, kt) do {                                                   \
    gload16(Bb + (size_t)((h) * 128) * K + (size_t)(kt) * 64,                    \
            lds + (d) * DSZ + ASZ + (h) * 8192 + tid * 8);                       \
    gload16(Bb + (size_t)((h) * 128 + 64) * K + (size_t)(kt) * 64,               \
            lds + (d) * DSZ + ASZ + (h) * 8192 + 4096 + tid * 8); } while (0)

    int aoff[MF][2], boff[4][2];
#pragma unroll
    for (int m = 0; m < MF; ++m) {
        int R = wr * (BM / 2) + m * 16 + l15;
#pragma unroll
        for (int ks = 0; ks < 2; ++ks)
            aoff[m][ks] = R * 64 + (((ks * 4 + l16) ^ (R & 7)) * 8);
    }
#pragma unroll
    for (int n = 0; n < 4; ++n) {
        int R = wc * 64 + n * 16 + l15;
#pragma unroll
        for (int ks = 0; ks < 2; ++ks)
            boff[n][ks] = ASZ + R * 64 + (((ks * 4 + l16) ^ (R & 7)) * 8);
    }

    f32x4 acc[MF][4] = {};
    half8 bfr[4][2];
    const int nj = K >> 7;

    STAGE_A(0, 0);
    STAGE_B(0, 0, 0); STAGE_B(0, 1, 0);
    STAGE_B(1, 0, 1); STAGE_B(1, 1, 1);
    VMW(4);
    __builtin_amdgcn_s_barrier();
    __builtin_amdgcn_sched_barrier(0);

#define PH(TT, Q, STAGECODE, VMCODE) do {                                        \
    const int dB_ = (TT) * DSZ;                                                  \
    half8 af_[AQ][2];                                                            \
    if ((Q) == 0) {                                                              \
        _Pragma("unroll") for (int n_ = 0; n_ < 4; ++n_)                         \
        _Pragma("unroll") for (int ks_ = 0; ks_ < 2; ++ks_)                      \
            bfr[n_][ks_] = *(const half8*)(lds + dB_ + boff[n_][ks_]);           \
    }                                                                            \
    _Pragma("unroll") for (int a_ = 0; a_ < AQ; ++a_)                            \
    _Pragma("unroll") for (int ks_ = 0; ks_ < 2; ++ks_)                          \
        af_[a_][ks_] = *(const half8*)(lds + dB_ + aoff[(Q) * AQ + a_][ks_]);    \
    STAGECODE;                                                                   \
    __builtin_amdgcn_s_barrier();                                                \
    asm volatile("s_waitcnt lgkmcnt(0)" ::: "memory");                           \
    __builtin_amdgcn_sched_barrier(0);                                           \
    __builtin_amdgcn_s_setprio(1);                                               \
    _Pragma("unroll") for (int ks_ = 0; ks_ < 2; ++ks_)                          \
    _Pragma("unroll") for (int a_ = 0; a_ < AQ; ++a_)                            \
    _Pragma("unroll") for (int n_ = 0; n_ < 4; ++n_)                             \
        acc[(Q) * AQ + a_][n_] = __builtin_amdgcn_mfma_f32_16x16x32_f16(         \
            af_[a_][ks_], bfr[n_][ks_], acc[(Q) * AQ + a_][n_], 0, 0, 0);        \
    __builtin_amdgcn_s_setprio(0);                                               \
    __builtin_amdgcn_sched_barrier(0);                                           \
    VMCODE;                                                                      \
    __builtin_amdgcn_s_barrier();                                                \
} while (0)

    for (int j = 0; j < nj; ++j) {
        const bool pf = (j + 1 < nj);
        const int t1 = 2 * j + 1, tn0 = 2 * j + 2, tn1 = 2 * j + 3;
        PH(0, 0, { STAGE_A(1, t1); }, {});
        PH(0, 1, { if (pf) STAGE_B(0, 0, tn0); }, {});
        PH(0, 2, { if (pf) STAGE_B(0, 1, tn0); }, {});
        PH(0, 3, {}, { if (pf) { VMW(4); } else { VMW(0); } });
        PH(1, 0, { if (pf) STAGE_A(0, tn0); }, {});
        PH(1, 1, {}, {});
        PH(1, 2, { if (pf) STAGE_B(1, 0, tn1); }, {});
        PH(1, 3, { if (pf) STAGE_B(1, 1, tn1); }, { if (pf) VMW(4); });
    }
#undef PH
#undef STAGE_A
#undef STAGE_B

    const int sel = bn >> 11;
    _Float16* __restrict__ C = sel == 0 ? C0 : sel == 1 ? C1 : sel == 2 ? C2 : C3;
    const int ccol0 = bn & 2047;
    _Float16* bb = lds;
#pragma unroll
    for (int p = 0; p < 2; ++p) {
        if (p) __syncthreads();
        if (wr == p) {
#pragma unroll
            for (int m = 0; m < MF; ++m)
#pragma unroll
                for (int n = 0; n < 4; ++n)
#pragma unroll
                    for (int r = 0; r < 4; ++r)
                        bb[(m * 16 + l16 * 4 + r) * 264 + wc * 64 + n * 16 + l15] =
                            (_Float16)acc[m][n][r];
        }
        __syncthreads();
#pragma unroll
        for (int rep = 0; rep < 8; ++rep) {
            int u = rep * 512 + tid;
            int i = u >> 5, q = u & 31;
            *(half8*)(C + (size_t)(bm + p * 128 + i) * 2048 + ccol0 + q * 8) =
                *(const half8*)(bb + i * 264 + q * 8);
        }
    }
}

// ---------------------------------------------------------------------------
// Occupancy-2 pipelined GEMM for the Wo matmul: BM x 128, BK=32, 8 waves
// (4M x 2N), 3 LDS buffers, counted vmcnt, verified swizzle. BM=128 ->
// 512 WGs, LDS 67.6KB -> 2 blocks/CU (stall-filling co-residency).
// ---------------------------------------------------------------------------
template <int BM, typename OT>
__global__ __launch_bounds__(512, 4) void gemmp(const _Float16* __restrict__ A,
                                                const _Float16* __restrict__ Bt,
                                                OT* __restrict__ C0, OT* __restrict__ C1,
                                                OT* __restrict__ C2, OT* __restrict__ C3,
                                                int K, int nx, int cpx)
{
    constexpr int BN   = 128;
    constexpr int LPT  = (BM + BN) / 128;
    constexpr int WR   = BM / 4;
    constexpr int MF   = WR / 16;
    constexpr int ASZ  = BM * 32;
    constexpr int DSZ  = (BM + BN) * 32;
    constexpr int VE   = 16 / sizeof(OT);
    constexpr int CPR  = 128 / VE;
    constexpr int BW   = 128 + VE;
    constexpr int BROWS = (BM == 256) ? 128 : BM;     // bounce rows per pass
    constexpr size_t STAGEB = (size_t)3 * DSZ * 2;
    constexpr size_t BOUNB  = (size_t)BROWS * BW * sizeof(OT);
    constexpr size_t LB = STAGEB > BOUNB ? STAGEB : BOUNB;
    __shared__ alignas(16) char ldsraw[LB];
    _Float16* lds = reinterpret_cast<_Float16*>(ldsraw);

    const int tid = threadIdx.x;
    const int lane = tid & 63, w = tid >> 6;
    const int wr = w >> 1, wc = w & 1;
    const int l15 = lane & 15, l16 = lane >> 4;

    const int bid = blockIdx.x;
    const int swz = (bid & 7) * cpx + (bid >> 3);
    const int bm = (swz / nx) * BM, bn = (swz % nx) * BN;

    const _Float16* src[LPT];
    int ldst[LPT];
#pragma unroll
    for (int ld = 0; ld < LPT; ++ld) {
        int F = ld * 512 + tid;
        int R = F >> 2;
        int sc = (F & 3) ^ (((R >> 3) & 1) << 1);
        src[ld] = (R < BM) ? A + (size_t)(bm + R) * K + sc * 8
                           : Bt + (size_t)(bn + R - BM) * K + sc * 8;
        ldst[ld] = F * 8;
    }

    int aoff[MF], boff[4];
#pragma unroll
    for (int m = 0; m < MF; ++m) {
        int R = wr * WR + m * 16 + l15;
        aoff[m] = R * 32 + ((l16 ^ (((R >> 3) & 1) << 1)) * 8);
    }
#pragma unroll
    for (int n = 0; n < 4; ++n) {
        int R = wc * 64 + n * 16 + l15;
        boff[n] = ASZ + R * 32 + ((l16 ^ (((R >> 3) & 1) << 1)) * 8);
    }

    f32x4 acc[MF][4] = {};
    const int nt = K >> 5;

#define STAGE(kt, buf) do { _Pragma("unroll")                                  \
    for (int ld_ = 0; ld_ < LPT; ++ld_)                                        \
        gload16(src[ld_] + (size_t)(kt) * 32, lds + (buf) * DSZ + ldst[ld_]);  \
    } while (0)
#define VM_STEADY() do { if constexpr (LPT == 3) VMW(3); else VMW(2); } while (0)

    STAGE(0, 0);
    STAGE(1, 1);
    VM_STEADY();
    __builtin_amdgcn_s_barrier();
    __builtin_amdgcn_sched_barrier(0);

    int cb = 0, nb = 2;
    for (int t = 0; t < nt; ++t) {
        const _Float16* L = lds + cb * DSZ;
        half8 af[MF], bf[4];
#pragma unroll
        for (int m = 0; m < MF; ++m) af[m] = *(const half8*)(L + aoff[m]);
#pragma unroll
        for (int n = 0; n < 4; ++n) bf[n] = *(const half8*)(L + boff[n]);

        const bool pf = (t + 2 < nt);
        if (pf) STAGE(t + 2, nb);

        asm volatile("s_waitcnt lgkmcnt(0)" ::: "memory");
        __builtin_amdgcn_sched_barrier(0);
        __builtin_amdgcn_s_setprio(1);
#pragma unroll
        for (int m = 0; m < MF; ++m)
#pragma unroll
            for (int n = 0; n < 4; ++n)
                acc[m][n] = __builtin_amdgcn_mfma_f32_16x16x32_f16(af[m], bf[n], acc[m][n], 0, 0, 0);
        __builtin_amdgcn_s_setprio(0);
        __builtin_amdgcn_sched_barrier(0);

        if (pf) VM_STEADY();
        else    VMW(0);
        __builtin_amdgcn_s_barrier();
        __builtin_amdgcn_sched_barrier(0);

        cb = (cb == 2) ? 0 : cb + 1;
        nb = (nb == 2) ? 0 : nb + 1;
    }
#undef STAGE
#undef VM_STEADY

    const int sel = bn >> 11;
    OT* __restrict__ C = sel == 0 ? C0 : sel == 1 ? C1 : sel == 2 ? C2 : C3;
    const int ccol0 = bn & 2047;
    OT* bb = reinterpret_cast<OT*>(ldsraw);

    if constexpr (BM == 256) {
#pragma unroll
        for (int p = 0; p < 2; ++p) {
            if (p) __syncthreads();
            if ((wr >> 1) == p) {
                const int rb = (wr & 1) * 64;
#pragma unroll
                for (int m = 0; m < MF; ++m)
#pragma unroll
                    for (int n = 0; n < 4; ++n)
#pragma unroll
                        for (int r = 0; r < 4; ++r)
                            bb[(rb + m * 16 + l16 * 4 + r) * BW + wc * 64 + n * 16 + l15] =
                                (OT)acc[m][n][r];
            }
            __syncthreads();
#pragma unroll
            for (int rep = 0; rep < (128 * CPR) / 512; ++rep) {
                int u = rep * 512 + tid;
                int i = u / CPR, q = u % CPR;
                if constexpr (sizeof(OT) == 2)
                    *reinterpret_cast<half8*>(C + (size_t)(bm + p * 128 + i) * 2048 + ccol0 + q * VE) =
                        *reinterpret_cast<const half8*>(bb + i * BW + q * VE);
                else
                    *reinterpret_cast<float4*>(C + (size_t)(bm + p * 128 + i) * 2048 + ccol0 + q * VE) =
                        *reinterpret_cast<const float4*>(bb + i * BW + q * VE);
            }
        }
    } else {
        // single-pass bounce: all BM rows at once
        __syncthreads();
#pragma unroll
        for (int m = 0; m < MF; ++m)
#pragma unroll
            for (int n = 0; n < 4; ++n)
#pragma unroll
                for (int r = 0; r < 4; ++r)
                    bb[(wr * WR + m * 16 + l16 * 4 + r) * BW + wc * 64 + n * 16 + l15] =
                        (OT)acc[m][n][r];
        __syncthreads();
#pragma unroll
        for (int rep = 0; rep < (BM * CPR) / 512; ++rep) {
            int u = rep * 512 + tid;
            int i = u / CPR, q = u % CPR;
            if constexpr (sizeof(OT) == 2)
                *reinterpret_cast<half8*>(C + (size_t)(bm + i) * 2048 + ccol0 + q * VE) =
                    *reinterpret_cast<const half8*>(bb + i * BW + q * VE);
            else
                *reinterpret_cast<float4*>(C + (size_t)(bm + i) * 2048 + ccol0 + q * VE) =
                    *reinterpret_cast<const float4*>(bb + i * BW + q * VE);
        }
    }
}

// ---------------------------------------------------------------------------
// R1 (conv fused): per (bh, chunk) U_c = sum_s bet*decay^(63-s) v_s k_s^T.
// Also EXPORTS conv'd kh (normalized) and vh so r3 need not recompute them.
// ---------------------------------------------------------------------------
__global__ __launch_bounds__(256) void r1_kernel(const _Float16* __restrict__ pk,
                                                 const _Float16* __restrict__ pv,
                                                 const float* __restrict__ kw,
                                                 const float* __restrict__ kb,
                                                 const float* __restrict__ vw,
                                                 const float* __restrict__ vb,
                                                 const float* __restrict__ A_log,
                                                 const float* __restrict__ beta,
                                                 _Float16* __restrict__ U,
                                                 _Float16* __restrict__ kh,
                                                 _Float16* __restrict__ vh)
{
    const int c = blockIdx.x & 31, bh = blockIdx.x >> 5;
    const int h = bh & 15, b = bh >> 4;
    const float decay = sigmoidf_(A_log[h]);
    const float bet = sigmoidf_(beta[h]);
    const float ld = logf(decay);

    __shared__ _Float16 sm[2 * 128 * 72];
    _Float16* kt = sm;
    _Float16* vt = sm + 128 * 72;

    const int tid = threadIdx.x;

#pragma unroll
    for (int rep = 0; rep < 4; ++rep) {
        int s = rep * 16 + (tid >> 4);
        int dq = tid & 15;
        int t = c * 64 + s;
        int ch = h * 128 + dq * 8;
        size_t rb = ((size_t)(b * T_ + t)) * DIM_ + ch;
        float ka[8], va[8];
        conv8(pk, kw, kb, rb, t, ch, ka);
        conv8(pv, vw, vb, rb, t, ch, va);
        float ss = 0.0f;
#pragma unroll
        for (int u = 0; u < 8; ++u) {
            ka[u] = ka[u] * sigmoidf_(ka[u]);
            ss += ka[u] * ka[u];
        }
        ss += __shfl_xor(ss, 1);
        ss += __shfl_xor(ss, 2);
        ss += __shfl_xor(ss, 4);
        ss += __shfl_xor(ss, 8);
        float sc = 1.0f / fmaxf(sqrtf(ss), 1e-12f);
        float vsc = bet * __expf(ld * (float)(63 - s));
        half8 k8, v8;
#pragma unroll
        for (int u = 0; u < 8; ++u) {
            k8[u] = (_Float16)(ka[u] * sc);
            v8[u] = (_Float16)va[u];
            kt[tsw(dq * 8 + u, s)] = k8[u];
            vt[tsw(dq * 8 + u, s)] = (_Float16)(vsc * va[u]);
        }
        *(half8*)(kh + rb) = k8;   // export for r3 (identical rounding path)
        *(half8*)(vh + rb) = v8;
    }
    __syncthreads();

    const int lane = tid & 63, w = tid >> 6;
    const int l15 = lane & 15, l16 = lane >> 4;
    f32x4 acc[2][8] = {};
#pragma unroll
    for (int ks = 0; ks < 2; ++ks) {
        half8 a0 = *(const half8*)(vt + tswb(w * 32 + l15,      ks * 4 + l16));
        half8 a1 = *(const half8*)(vt + tswb(w * 32 + 16 + l15, ks * 4 + l16));
#pragma unroll
        for (int fj = 0; fj < 8; ++fj) {
            half8 bf = *(const half8*)(kt + tswb(fj * 16 + l15, ks * 4 + l16));
            acc[0][fj] = __builtin_amdgcn_mfma_f32_16x16x32_f16(a0, bf, acc[0][fj], 0, 0, 0);
            acc[1][fj] = __builtin_amdgcn_mfma_f32_16x16x32_f16(a1, bf, acc[1][fj], 0, 0, 0);
        }
    }
    __syncthreads();

    _Float16* buf = sm;
#pragma unroll
    for (int fi = 0; fi < 2; ++fi)
#pragma unroll
        for (int fj = 0; fj < 8; ++fj)
#pragma unroll
            for (int r = 0; r < 4; ++r)
                buf[(w * 32 + fi * 16 + l16 * 4 + r) * 136 + fj * 16 + l15] =
                    (_Float16)acc[fi][fj][r];
    __syncthreads();

    _Float16* Ub = U + (((size_t)blockIdx.x) << 14);
#pragma unroll
    for (int rep = 0; rep < 8; ++rep) {
        int u = rep * 256 + tid;
        int i = u >> 4, jq = u & 15;
        *(half8*)(Ub + i * 128 + jq * 8) = *(const half8*)(buf + i * 136 + jq * 8);
    }
}

// ---------------------------------------------------------------------------
// R2: chunk-boundary state scan; 512 blocks x 128 threads, 4-deep prefetch.
// Output Sst in FRAGMENT-ORDERED layout (see round-14 note).
// ---------------------------------------------------------------------------
__global__ __launch_bounds__(128) void r2_kernel(const _Float16* __restrict__ U,
                                                 _Float16* __restrict__ S,
                                                 const float* __restrict__ A_log)
{
    const int blk = blockIdx.x;
    const int bh = blk >> 4, part = blk & 15, h = bh & 15;
    const float decay = sigmoidf_(A_log[h]);
    const float d64 = __expf(64.0f * logf(decay));
    const int tid = threadIdx.x;
    const size_t base = ((size_t)bh << 19) + (size_t)part * 1024 + (size_t)tid * 8;
    const half8* Up = (const half8*)(U + base);

    const int v  = part * 8 + (tid >> 4);
    const int d0 = (tid & 15) * 8;
    const int nf = v >> 4, l15 = v & 15;
    const int kd = d0 >> 5, l16 = (d0 >> 3) & 3;
    half8* Sp = (half8*)(S + ((size_t)bh << 19) +
                         (size_t)(((nf * 4 + kd) * 64) + l16 * 16 + l15) * 8);

    float st[8] = {0, 0, 0, 0, 0, 0, 0, 0};
    half8 pfb[4];
#pragma unroll
    for (int i = 0; i < 4; ++i) pfb[i] = Up[(size_t)i * 2048];
    for (int c = 0; c < 32; ++c) {
        half8 cur = pfb[c & 3];
        if (c + 4 < 32) pfb[c & 3] = Up[(size_t)(c + 4) * 2048];
        half8 so;
#pragma unroll
        for (int i = 0; i < 8; ++i) {
            so[i] = (_Float16)st[i];
            st[i] = d64 * st[i] + (float)cur[i];
        }
        Sp[(size_t)c * 2048] = so;
    }
}

// ---------------------------------------------------------------------------
// R3: out = mask(QK^T)V + rowscale(Q S^T), gated. Reads pre-conv'd kh/vh
// from r1; S fragments read coalesced from r2's fragment-ordered layout.
// ---------------------------------------------------------------------------
__global__ __launch_bounds__(256) void r3_kernel(const _Float16* __restrict__ pq,
                                                 const _Float16* __restrict__ kh,
                                                 const _Float16* __restrict__ vh,
                                                 const _Float16* __restrict__ S,
                                                 const _Float16* __restrict__ pg,
                                                 const float* __restrict__ qw,
                                                 const float* __restrict__ qb,
                                                 const float* __restrict__ A_log,
                                                 const float* __restrict__ beta,
                                                 _Float16* __restrict__ gated)
{
    const int c = blockIdx.x & 31, bh = blockIdx.x >> 5;
    const int h = bh & 15, b = bh >> 4;
    const float decay = sigmoidf_(A_log[h]);
    const float bet = sigmoidf_(beta[h]);
    const float ld = logf(decay);

    __shared__ _Float16 vt[128 * 72];       // [n][s] swizzled (tsw)
    __shared__ _Float16 kbuf[64 * 136];     // k; reused as out bounce
    __shared__ _Float16 qps[64 * 136];      // conv'd q; reused as masked-P
    __shared__ float e1[65];

    const int tid = threadIdx.x;
    if (tid < 65) e1[tid] = __expf(ld * (float)tid);

#pragma unroll
    for (int rep = 0; rep < 4; ++rep) {
        int s = rep * 16 + (tid >> 4);
        int nq = tid & 15;
        int t = c * 64 + s;
        int ch = h * 128 + nq * 8;
        size_t rb = ((size_t)(b * T_ + t)) * DIM_ + ch;
        half8 k8 = *(const half8*)(kh + rb);
        half8 v8 = *(const half8*)(vh + rb);
        float qa[8];
        conv8(pq, qw, qb, rb, t, ch, qa);
        half8 q8;
#pragma unroll
        for (int u = 0; u < 8; ++u) {
            float q = qa[u];
            q8[u] = (_Float16)(q * sigmoidf_(q));
            vt[tsw(nq * 8 + u, s)] = v8[u];
        }
        *(half8*)(kbuf + s * 136 + ((nq ^ (s & 7)) * 8)) = k8;
        *(half8*)(qps + s * 136 + ((nq ^ (s & 7)) * 8)) = q8;
    }
    __syncthreads();

    const int lane = tid & 63, w = tid >> 6;
    const int l15 = lane & 15, l16 = lane >> 4;
    const int qr = w * 16 + l15;

    half8 af[4];
#pragma unroll
    for (int kd = 0; kd < 4; ++kd)
        af[kd] = *(const half8*)(qps + qr * 136 + (((kd * 4 + l16) ^ (qr & 7)) * 8));
    __syncthreads();   // all waves hold Q in regs before qps is overwritten

    f32x4 pacc[4] = {};
#pragma unroll
    for (int sf = 0; sf < 4; ++sf) {
        int s = sf * 16 + l15;
#pragma unroll
        for (int kd = 0; kd < 4; ++kd) {
            half8 bf = *(const half8*)(kbuf + s * 136 + (((kd * 4 + l16) ^ (s & 7)) * 8));
            pacc[sf] = __builtin_amdgcn_mfma_f32_16x16x32_f16(af[kd], bf, pacc[sf], 0, 0, 0);
        }
    }
#pragma unroll
    for (int sf = 0; sf < 4; ++sf)
#pragma unroll
        for (int r = 0; r < 4; ++r) {
            int tl = w * 16 + l16 * 4 + r;
            int s = sf * 16 + l15;
            float f = (s <= tl) ? bet * e1[tl - s] : 0.0f;
            qps[tl * 72 + s] = (_Float16)(pacc[sf][r] * f);   // ps[tl][s]
        }
    __syncthreads();

    half8 pf[2];
#pragma unroll
    for (int ks = 0; ks < 2; ++ks)
        pf[ks] = *(const half8*)(qps + (w * 16 + l15) * 72 + ks * 32 + l16 * 8);

    f32x4 acc1[8] = {};
    f32x4 acc2[8] = {};
    const _Float16* Sb = S + (((size_t)blockIdx.x) << 14);
#pragma unroll
    for (int nf = 0; nf < 8; ++nf) {
#pragma unroll
        for (int kd = 0; kd < 4; ++kd) {
            half8 bf = *(const half8*)(Sb + (size_t)((nf * 4 + kd) * 64 + lane) * 8);
            acc1[nf] = __builtin_amdgcn_mfma_f32_16x16x32_f16(af[kd], bf, acc1[nf], 0, 0, 0);
        }
#pragma unroll
        for (int ks = 0; ks < 2; ++ks) {
            half8 bf = *(const half8*)(vt + tswb(nf * 16 + l15, ks * 4 + l16));
            acc2[nf] = __builtin_amdgcn_mfma_f32_16x16x32_f16(pf[ks], bf, acc2[nf], 0, 0, 0);
        }
    }
#pragma unroll
    for (int nf = 0; nf < 8; ++nf)
#pragma unroll
        for (int r = 0; r < 4; ++r) {
            int tl = w * 16 + l16 * 4 + r;
            float o = acc2[nf][r] + e1[tl + 1] * acc1[nf][r];
            kbuf[tl * 136 + nf * 16 + l15] = (_Float16)o;
        }
    __syncthreads();

#pragma unroll
    for (int rep = 0; rep < 4; ++rep) {
        int u = rep * 256 + tid;
        int tl = u >> 4, jq = u & 15;
        size_t row = (size_t)(b * T_ + c * 64 + tl);
        half8 o8 = *(const half8*)(kbuf + tl * 136 + jq * 8);
        half8 g8 = *(const half8*)(pg + row * DIM_ + h * 128 + jq * 8);
        half8 r8;
#pragma unroll
        for (int j = 0; j < 8; ++j)
            r8[j] = (_Float16)((float)o8[j] * sigmoidf_((float)g8[j]));
        *(half8*)(gated + row * DIM_ + h * 128 + jq * 8) = r8;
    }
}

// ---------------------------------------------------------------------------
extern "C" void kernel_launch(void* const* d_in, const int* in_sizes, int n_in,
                              void* d_out, int out_size, void* d_ws, size_t ws_size,
                              hipStream_t stream)
{
    const float* x     = (const float*)d_in[0];
    const float* Wq    = (const float*)d_in[1];
    const float* Wk    = (const float*)d_in[2];
    const float* Wv    = (const float*)d_in[3];
    const float* Wo    = (const float*)d_in[4];
    const float* Wg    = (const float*)d_in[5];
    const float* qw    = (const float*)d_in[6];
    const float* qb    = (const float*)d_in[7];
    const float* kw    = (const float*)d_in[8];
    const float* kb    = (const float*)d_in[9];
    const float* vw    = (const float*)d_in[10];
    const float* vb    = (const float*)d_in[11];
    const float* beta  = (const float*)d_in[12];
    const float* A_log = (const float*)d_in[13];
    float* out = (float*)d_out;

    char* wsb = (char*)d_ws;
    const size_t WT  = (size_t)DIM_ * DIM_ * 2;
    const size_t SZ  = (size_t)B_ * T_ * DIM_;
    const size_t SZH = SZ * 2;

    _Float16* wtq = (_Float16*)(wsb + 0 * WT);    // wtq..wtg contiguous = Bt[8192][2048]
    _Float16* wto = (_Float16*)(wsb + 4 * WT);
    char* pbase = wsb + 5 * WT;
    _Float16* pq = (_Float16*)(pbase + 0 * SZH);  // raw q projection (live to r3)
    _Float16* pk = (_Float16*)(pbase + 1 * SZH);  // raw k projection (dead after r1)
    _Float16* pv = (_Float16*)(pbase + 2 * SZH);  // raw v projection (dead after r1)
    _Float16* xh = (_Float16*)(pbase + 3 * SZH);  // dead after proj GEMM
    _Float16* pg = (_Float16*)(pbase + 4 * SZH);  // live to r3
    _Float16* U    = (_Float16*)(pbase + 5 * SZH);  // 32 MB (slots 5-6)
    _Float16* Sst  = (_Float16*)(pbase + 7 * SZH);  // 32 MB (slots 7-8)
    _Float16* kh   = xh;                            // conv'd k (xh dead)
    _Float16* vh   = (_Float16*)(pbase + 9 * SZH);  // conv'd v (new slot)
    _Float16* gated = U;                            // U dead after r2

    // cvt + 5 weight transposes in one launch (vectorized)
    prep<<<dim3(32, 32, 6), 256, 0, stream>>>(Wq, Wk, Wv, Wg, Wo, wtq, x, xh);

    // fused projections: M=4096, N=8192 (q|k|v|g): 16x32 = 512 tiles of 256^2
    gemm8ph<256><<<512, 512, 0, stream>>>(xh, wtq, pq, pk, pv, pg,
                                          DIM_, 32, 64);

    r1_kernel<<<B_ * H_ * 32, 256, 0, stream>>>(pk, pv, kw, kb, vw, vb,
                                                A_log, beta, U, kh, vh);
    r2_kernel<<<512, 128, 0, stream>>>(U, Sst, A_log);
    r3_kernel<<<B_ * H_ * 32, 256, 0, stream>>>(pq, kh, vh, Sst, pg,
                                                qw, qb, A_log, beta, gated);

    // out = gated @ Wo : M=4096, N=2048 -> 32x16 = 512 tiles of 128x128
    gemmp<128, float><<<512, 512, 0, stream>>>(gated, wto, out, out, out, out,
                                               DIM_, 16, 64);
}

// Round 16
// 329.096 us; speedup vs baseline: 1.4071x; 1.4071x over previous
//
#include <hip/hip_runtime.h>
#include <math.h>

#define B_   2
#define T_   2048
#define DIM_ 2048
#define H_   16

typedef __attribute__((ext_vector_type(8))) _Float16 half8;
typedef __attribute__((ext_vector_type(4))) float f32x4;

__device__ __forceinline__ float sigmoidf_(float x) { return 1.0f / (1.0f + __expf(-x)); }

__device__ __forceinline__ void gload16(const _Float16* g, _Float16* l) {
    __builtin_amdgcn_global_load_lds((const __attribute__((address_space(1))) void*)g,
                                     (__attribute__((address_space(3))) void*)l, 16, 0, 0);
}

#define VMW(n) asm volatile("s_waitcnt vmcnt(" #n ")" ::: "memory")

// Swizzled transpose-LDS addressing for [row][72] f16 tiles holding [row][s].
__device__ __forceinline__ int tsw(int row, int s) {
    return row * 72 + ((((s >> 3) ^ ((row >> 3) & 7)) << 3) | (s & 7));
}
__device__ __forceinline__ int tswb(int row, int sb) {
    return row * 72 + (((sb ^ ((row >> 3) & 7)) << 3));
}

// Depthwise causal conv K=4, 8 channels, fp32 math.
__device__ __forceinline__ void conv8(const _Float16* __restrict__ src,
                                      const float* __restrict__ w,
                                      const float* __restrict__ bias,
                                      size_t rb, int t, int ch, float* acc)
{
    float4 w4[8];
#pragma unroll
    for (int u = 0; u < 8; ++u) {
        w4[u] = *(const float4*)(w + (ch + u) * 4);
        acc[u] = bias[ch + u];
    }
#pragma unroll
    for (int j = 0; j < 4; ++j) {
        if (t - 3 + j >= 0) {
            half8 xv = *(const half8*)(src + rb + (ptrdiff_t)(j - 3) * DIM_);
#pragma unroll
            for (int u = 0; u < 8; ++u)
                acc[u] += (float)xv[u] * ((const float*)&w4[u])[j];
        }
    }
}

// ---------------------------------------------------------------------------
// prep: z<5 -> weight transpose W[K][N] f32 -> Wt[N][K] f16 (vectorized);
//       z==5 -> x f32->f16 cvt.
// ---------------------------------------------------------------------------
__global__ __launch_bounds__(256) void prep(const float* __restrict__ W0,
                                            const float* __restrict__ W1,
                                            const float* __restrict__ W2,
                                            const float* __restrict__ W3,
                                            const float* __restrict__ W4,
                                            _Float16* __restrict__ wbase,
                                            const float* __restrict__ x,
                                            _Float16* __restrict__ xh)
{
    const int z = blockIdx.z;
    if (z == 5) {
        size_t blk = ((size_t)blockIdx.y * 32 + blockIdx.x) * 8192;
#pragma unroll
        for (int j = 0; j < 4; ++j) {
            size_t i = blk + (size_t)j * 2048 + (size_t)threadIdx.x * 8;
            float4 a = *(const float4*)(x + i);
            float4 b = *(const float4*)(x + i + 4);
            half8 h;
            h[0] = (_Float16)a.x; h[1] = (_Float16)a.y; h[2] = (_Float16)a.z; h[3] = (_Float16)a.w;
            h[4] = (_Float16)b.x; h[5] = (_Float16)b.y; h[6] = (_Float16)b.z; h[7] = (_Float16)b.w;
            *(half8*)(xh + i) = h;
        }
        return;
    }
    __shared__ float t[64 * 65];
    const float* W = z == 0 ? W0 : z == 1 ? W1 : z == 2 ? W2 : z == 3 ? W3 : W4;
    _Float16* Wt = wbase + (size_t)z * DIM_ * DIM_;
    const int n0 = blockIdx.x * 64, k0 = blockIdx.y * 64;
#pragma unroll
    for (int rep = 0; rep < 4; ++rep) {
        int row = rep * 16 + (threadIdx.x >> 4);
        int qc = threadIdx.x & 15;
        float4 v = *(const float4*)(W + (size_t)(k0 + row) * DIM_ + n0 + qc * 4);
        t[row * 65 + qc * 4 + 0] = v.x;
        t[row * 65 + qc * 4 + 1] = v.y;
        t[row * 65 + qc * 4 + 2] = v.z;
        t[row * 65 + qc * 4 + 3] = v.w;
    }
    __syncthreads();
#pragma unroll
    for (int rep = 0; rep < 2; ++rep) {
        int r = rep * 32 + (threadIdx.x >> 3);
        int q = threadIdx.x & 7;
        half8 o;
#pragma unroll
        for (int j = 0; j < 8; ++j)
            o[j] = (_Float16)t[(q * 8 + j) * 65 + r];
        *(half8*)(Wt + (size_t)(n0 + r) * DIM_ + k0 + q * 8) = o;
    }
}

// ---------------------------------------------------------------------------
// 8-phase pipelined MFMA GEMM (measured-best on proj): 256x256 tile, BK=64,
// 2 K-tiles/iter, 8 waves (2M x 4N), counted vmcnt(4), 3-bit XOR swizzle.
// Epilogue: two-pass LDS bounce -> coalesced half8 stores.
// ---------------------------------------------------------------------------
template <int BM>
__global__ __launch_bounds__(512, 1) void gemm8ph(const _Float16* __restrict__ A,
                                                  const _Float16* __restrict__ Bt,
                                                  _Float16* __restrict__ C0, _Float16* __restrict__ C1,
                                                  _Float16* __restrict__ C2, _Float16* __restrict__ C3,
                                                  int K, int nx, int cpx)
{
    constexpr int MF  = BM / 32;
    constexpr int AQ  = MF / 4;
    constexpr int ASZ = BM * 64;
    constexpr int DSZ = (BM + 256) * 64;
    __shared__ _Float16 lds[2 * DSZ];

    const int tid = threadIdx.x;
    const int lane = tid & 63, w = tid >> 6;
    const int wr = w >> 2, wc = w & 3;
    const int l15 = lane & 15, l16 = lane >> 4;

    const int bid = blockIdx.x;
    const int swz = (bid & 7) * cpx + (bid >> 3);
    const int bm = (swz / nx) * BM, bn = (swz % nx) * 256;

    const int r0 = tid >> 3;
    const int c0 = ((tid & 7) ^ (r0 & 7)) * 8;
    const _Float16* Ab = A + (size_t)(bm + r0) * K + c0;
    const _Float16* Bb = Bt + (size_t)(bn + r0) * K + c0;

#define STAGE_A(d, kt) do { _Pragma("unroll")                                    \
    for (int u = 0; u < BM / 64; ++u)                                            \
        gload16(Ab + (size_t)(u * 64) * K + (size_t)(kt) * 64,                   \
                lds + (d) * DSZ + u * 4096 + tid * 8); } while (0)
#define STAGE_B(d, h, kt) do {                                                   \
    gload16(Bb + (size_t)((h) * 128) * K + (size_t)(kt) * 64,                    \
            lds + (d) * DSZ + ASZ + (h) * 8192 + tid * 8);                       \
    gload16(Bb + (size_t)((h) * 128 + 64) * K + (size_t)(kt) * 64,               \
            lds + (d) * DSZ + ASZ + (h) * 8192 + 4096 + tid * 8); } while (0)

    int aoff[MF][2], boff[4][2];
#pragma unroll
    for (int m = 0; m < MF; ++m) {
        int R = wr * (BM / 2) + m * 16 + l15;
#pragma unroll
        for (int ks = 0; ks < 2; ++ks)
            aoff[m][ks] = R * 64 + (((ks * 4 + l16) ^ (R & 7)) * 8);
    }
#pragma unroll
    for (int n = 0; n < 4; ++n) {
        int R = wc * 64 + n * 16 + l15;
#pragma unroll
        for (int ks = 0; ks < 2; ++ks)
            boff[n][ks] = ASZ + R * 64 + (((ks * 4 + l16) ^ (R & 7)) * 8);
    }

    f32x4 acc[MF][4] = {};
    half8 bfr[4][2];
    const int nj = K >> 7;

    STAGE_A(0, 0);
    STAGE_B(0, 0, 0); STAGE_B(0, 1, 0);
    STAGE_B(1, 0, 1); STAGE_B(1, 1, 1);
    VMW(4);
    __builtin_amdgcn_s_barrier();
    __builtin_amdgcn_sched_barrier(0);

#define PH(TT, Q, STAGECODE, VMCODE) do {                                        \
    const int dB_ = (TT) * DSZ;                                                  \
    half8 af_[AQ][2];                                                            \
    if ((Q) == 0) {                                                              \
        _Pragma("unroll") for (int n_ = 0; n_ < 4; ++n_)                         \
        _Pragma("unroll") for (int ks_ = 0; ks_ < 2; ++ks_)                      \
            bfr[n_][ks_] = *(const half8*)(lds + dB_ + boff[n_][ks_]);           \
    }                                                                            \
    _Pragma("unroll") for (int a_ = 0; a_ < AQ; ++a_)                            \
    _Pragma("unroll") for (int ks_ = 0; ks_ < 2; ++ks_)                          \
        af_[a_][ks_] = *(const half8*)(lds + dB_ + aoff[(Q) * AQ + a_][ks_]);    \
    STAGECODE;                                                                   \
    __builtin_amdgcn_s_barrier();                                                \
    asm volatile("s_waitcnt lgkmcnt(0)" ::: "memory");                           \
    __builtin_amdgcn_sched_barrier(0);                                           \
    __builtin_amdgcn_s_setprio(1);                                               \
    _Pragma("unroll") for (int ks_ = 0; ks_ < 2; ++ks_)                          \
    _Pragma("unroll") for (int a_ = 0; a_ < AQ; ++a_)                            \
    _Pragma("unroll") for (int n_ = 0; n_ < 4; ++n_)                             \
        acc[(Q) * AQ + a_][n_] = __builtin_amdgcn_mfma_f32_16x16x32_f16(         \
            af_[a_][ks_], bfr[n_][ks_], acc[(Q) * AQ + a_][n_], 0, 0, 0);        \
    __builtin_amdgcn_s_setprio(0);                                               \
    __builtin_amdgcn_sched_barrier(0);                                           \
    VMCODE;                                                                      \
    __builtin_amdgcn_s_barrier();                                                \
} while (0)

    for (int j = 0; j < nj; ++j) {
        const bool pf = (j + 1 < nj);
        const int t1 = 2 * j + 1, tn0 = 2 * j + 2, tn1 = 2 * j + 3;
        PH(0, 0, { STAGE_A(1, t1); }, {});
        PH(0, 1, { if (pf) STAGE_B(0, 0, tn0); }, {});
        PH(0, 2, { if (pf) STAGE_B(0, 1, tn0); }, {});
        PH(0, 3, {}, { if (pf) { VMW(4); } else { VMW(0); } });
        PH(1, 0, { if (pf) STAGE_A(0, tn0); }, {});
        PH(1, 1, {}, {});
        PH(1, 2, { if (pf) STAGE_B(1, 0, tn1); }, {});
        PH(1, 3, { if (pf) STAGE_B(1, 1, tn1); }, { if (pf) VMW(4); });
    }
#undef PH
#undef STAGE_A
#undef STAGE_B

    const int sel = bn >> 11;
    _Float16* __restrict__ C = sel == 0 ? C0 : sel == 1 ? C1 : sel == 2 ? C2 : C3;
    const int ccol0 = bn & 2047;
    _Float16* bb = lds;
#pragma unroll
    for (int p = 0; p < 2; ++p) {
        if (p) __syncthreads();
        if (wr == p) {
#pragma unroll
            for (int m = 0; m < MF; ++m)
#pragma unroll
                for (int n = 0; n < 4; ++n)
#pragma unroll
                    for (int r = 0; r < 4; ++r)
                        bb[(m * 16 + l16 * 4 + r) * 264 + wc * 64 + n * 16 + l15] =
                            (_Float16)acc[m][n][r];
        }
        __syncthreads();
#pragma unroll
        for (int rep = 0; rep < 8; ++rep) {
            int u = rep * 512 + tid;
            int i = u >> 5, q = u & 31;
            *(half8*)(C + (size_t)(bm + p * 128 + i) * 2048 + ccol0 + q * 8) =
                *(const half8*)(bb + i * 264 + q * 8);
        }
    }
}

// ---------------------------------------------------------------------------
// Occupancy-2 pipelined GEMM for the Wo matmul: BM x 128, BK=32, 8 waves
// (4M x 2N), 3 LDS buffers, counted vmcnt, verified swizzle. BM=128 ->
// 512 WGs, LDS 67.6KB -> 2 blocks/CU (stall-filling co-residency).
// ---------------------------------------------------------------------------
template <int BM, typename OT>
__global__ __launch_bounds__(512, 4) void gemmp(const _Float16* __restrict__ A,
                                                const _Float16* __restrict__ Bt,
                                                OT* __restrict__ C0, OT* __restrict__ C1,
                                                OT* __restrict__ C2, OT* __restrict__ C3,
                                                int K, int nx, int cpx)
{
    constexpr int BN   = 128;
    constexpr int LPT  = (BM + BN) / 128;
    constexpr int WR   = BM / 4;
    constexpr int MF   = WR / 16;
    constexpr int ASZ  = BM * 32;
    constexpr int DSZ  = (BM + BN) * 32;
    constexpr int VE   = 16 / sizeof(OT);
    constexpr int CPR  = 128 / VE;
    constexpr int BW   = 128 + VE;
    constexpr int BROWS = (BM == 256) ? 128 : BM;
    constexpr size_t STAGEB = (size_t)3 * DSZ * 2;
    constexpr size_t BOUNB  = (size_t)BROWS * BW * sizeof(OT);
    constexpr size_t LB = STAGEB > BOUNB ? STAGEB : BOUNB;
    __shared__ alignas(16) char ldsraw[LB];
    _Float16* lds = reinterpret_cast<_Float16*>(ldsraw);

    const int tid = threadIdx.x;
    const int lane = tid & 63, w = tid >> 6;
    const int wr = w >> 1, wc = w & 1;
    const int l15 = lane & 15, l16 = lane >> 4;

    const int bid = blockIdx.x;
    const int swz = (bid & 7) * cpx + (bid >> 3);
    const int bm = (swz / nx) * BM, bn = (swz % nx) * BN;

    const _Float16* src[LPT];
    int ldst[LPT];
#pragma unroll
    for (int ld = 0; ld < LPT; ++ld) {
        int F = ld * 512 + tid;
        int R = F >> 2;
        int sc = (F & 3) ^ (((R >> 3) & 1) << 1);
        src[ld] = (R < BM) ? A + (size_t)(bm + R) * K + sc * 8
                           : Bt + (size_t)(bn + R - BM) * K + sc * 8;
        ldst[ld] = F * 8;
    }

    int aoff[MF], boff[4];
#pragma unroll
    for (int m = 0; m < MF; ++m) {
        int R = wr * WR + m * 16 + l15;
        aoff[m] = R * 32 + ((l16 ^ (((R >> 3) & 1) << 1)) * 8);
    }
#pragma unroll
    for (int n = 0; n < 4; ++n) {
        int R = wc * 64 + n * 16 + l15;
        boff[n] = ASZ + R * 32 + ((l16 ^ (((R >> 3) & 1) << 1)) * 8);
    }

    f32x4 acc[MF][4] = {};
    const int nt = K >> 5;

#define STAGE(kt, buf) do { _Pragma("unroll")                                  \
    for (int ld_ = 0; ld_ < LPT; ++ld_)                                        \
        gload16(src[ld_] + (size_t)(kt) * 32, lds + (buf) * DSZ + ldst[ld_]);  \
    } while (0)
#define VM_STEADY() do { if constexpr (LPT == 3) VMW(3); else VMW(2); } while (0)

    STAGE(0, 0);
    STAGE(1, 1);
    VM_STEADY();
    __builtin_amdgcn_s_barrier();
    __builtin_amdgcn_sched_barrier(0);

    int cb = 0, nb = 2;
    for (int t = 0; t < nt; ++t) {
        const _Float16* L = lds + cb * DSZ;
        half8 af[MF], bf[4];
#pragma unroll
        for (int m = 0; m < MF; ++m) af[m] = *(const half8*)(L + aoff[m]);
#pragma unroll
        for (int n = 0; n < 4; ++n) bf[n] = *(const half8*)(L + boff[n]);

        const bool pf = (t + 2 < nt);
        if (pf) STAGE(t + 2, nb);

        asm volatile("s_waitcnt lgkmcnt(0)" ::: "memory");
        __builtin_amdgcn_sched_barrier(0);
        __builtin_amdgcn_s_setprio(1);
#pragma unroll
        for (int m = 0; m < MF; ++m)
#pragma unroll
            for (int n = 0; n < 4; ++n)
                acc[m][n] = __builtin_amdgcn_mfma_f32_16x16x32_f16(af[m], bf[n], acc[m][n], 0, 0, 0);
        __builtin_amdgcn_s_setprio(0);
        __builtin_amdgcn_sched_barrier(0);

        if (pf) VM_STEADY();
        else    VMW(0);
        __builtin_amdgcn_s_barrier();
        __builtin_amdgcn_sched_barrier(0);

        cb = (cb == 2) ? 0 : cb + 1;
        nb = (nb == 2) ? 0 : nb + 1;
    }
#undef STAGE
#undef VM_STEADY

    const int sel = bn >> 11;
    OT* __restrict__ C = sel == 0 ? C0 : sel == 1 ? C1 : sel == 2 ? C2 : C3;
    const int ccol0 = bn & 2047;
    OT* bb = reinterpret_cast<OT*>(ldsraw);

    if constexpr (BM == 256) {
#pragma unroll
        for (int p = 0; p < 2; ++p) {
            if (p) __syncthreads();
            if ((wr >> 1) == p) {
                const int rb = (wr & 1) * 64;
#pragma unroll
                for (int m = 0; m < MF; ++m)
#pragma unroll
                    for (int n = 0; n < 4; ++n)
#pragma unroll
                        for (int r = 0; r < 4; ++r)
                            bb[(rb + m * 16 + l16 * 4 + r) * BW + wc * 64 + n * 16 + l15] =
                                (OT)acc[m][n][r];
            }
            __syncthreads();
#pragma unroll
            for (int rep = 0; rep < (128 * CPR) / 512; ++rep) {
                int u = rep * 512 + tid;
                int i = u / CPR, q = u % CPR;
                if constexpr (sizeof(OT) == 2)
                    *reinterpret_cast<half8*>(C + (size_t)(bm + p * 128 + i) * 2048 + ccol0 + q * VE) =
                        *reinterpret_cast<const half8*>(bb + i * BW + q * VE);
                else
                    *reinterpret_cast<float4*>(C + (size_t)(bm + p * 128 + i) * 2048 + ccol0 + q * VE) =
                        *reinterpret_cast<const float4*>(bb + i * BW + q * VE);
            }
        }
    } else {
        __syncthreads();
#pragma unroll
        for (int m = 0; m < MF; ++m)
#pragma unroll
            for (int n = 0; n < 4; ++n)
#pragma unroll
                for (int r = 0; r < 4; ++r)
                    bb[(wr * WR + m * 16 + l16 * 4 + r) * BW + wc * 64 + n * 16 + l15] =
                        (OT)acc[m][n][r];
        __syncthreads();
#pragma unroll
        for (int rep = 0; rep < (BM * CPR) / 512; ++rep) {
            int u = rep * 512 + tid;
            int i = u / CPR, q = u % CPR;
            if constexpr (sizeof(OT) == 2)
                *reinterpret_cast<half8*>(C + (size_t)(bm + i) * 2048 + ccol0 + q * VE) =
                    *reinterpret_cast<const half8*>(bb + i * BW + q * VE);
            else
                *reinterpret_cast<float4*>(C + (size_t)(bm + i) * 2048 + ccol0 + q * VE) =
                    *reinterpret_cast<const float4*>(bb + i * BW + q * VE);
        }
    }
}

// ---------------------------------------------------------------------------
// R1 (conv fused): per (bh, chunk) U_c = sum_s bet*decay^(63-s) v_s k_s^T.
// Also EXPORTS conv'd kh (normalized) and vh so r3 need not recompute them.
// ---------------------------------------------------------------------------
__global__ __launch_bounds__(256) void r1_kernel(const _Float16* __restrict__ pk,
                                                 const _Float16* __restrict__ pv,
                                                 const float* __restrict__ kw,
                                                 const float* __restrict__ kb,
                                                 const float* __restrict__ vw,
                                                 const float* __restrict__ vb,
                                                 const float* __restrict__ A_log,
                                                 const float* __restrict__ beta,
                                                 _Float16* __restrict__ U,
                                                 _Float16* __restrict__ kh,
                                                 _Float16* __restrict__ vh)
{
    const int c = blockIdx.x & 31, bh = blockIdx.x >> 5;
    const int h = bh & 15, b = bh >> 4;
    const float decay = sigmoidf_(A_log[h]);
    const float bet = sigmoidf_(beta[h]);
    const float ld = logf(decay);

    __shared__ _Float16 sm[2 * 128 * 72];
    _Float16* kt = sm;
    _Float16* vt = sm + 128 * 72;

    const int tid = threadIdx.x;

#pragma unroll
    for (int rep = 0; rep < 4; ++rep) {
        int s = rep * 16 + (tid >> 4);
        int dq = tid & 15;
        int t = c * 64 + s;
        int ch = h * 128 + dq * 8;
        size_t rb = ((size_t)(b * T_ + t)) * DIM_ + ch;
        float ka[8], va[8];
        conv8(pk, kw, kb, rb, t, ch, ka);
        conv8(pv, vw, vb, rb, t, ch, va);
        float ss = 0.0f;
#pragma unroll
        for (int u = 0; u < 8; ++u) {
            ka[u] = ka[u] * sigmoidf_(ka[u]);
            ss += ka[u] * ka[u];
        }
        ss += __shfl_xor(ss, 1);
        ss += __shfl_xor(ss, 2);
        ss += __shfl_xor(ss, 4);
        ss += __shfl_xor(ss, 8);
        float sc = 1.0f / fmaxf(sqrtf(ss), 1e-12f);
        float vsc = bet * __expf(ld * (float)(63 - s));
        half8 k8, v8;
#pragma unroll
        for (int u = 0; u < 8; ++u) {
            k8[u] = (_Float16)(ka[u] * sc);
            v8[u] = (_Float16)va[u];
            kt[tsw(dq * 8 + u, s)] = k8[u];
            vt[tsw(dq * 8 + u, s)] = (_Float16)(vsc * va[u]);
        }
        *(half8*)(kh + rb) = k8;   // export for r3 (identical rounding path)
        *(half8*)(vh + rb) = v8;
    }
    __syncthreads();

    const int lane = tid & 63, w = tid >> 6;
    const int l15 = lane & 15, l16 = lane >> 4;
    f32x4 acc[2][8] = {};
#pragma unroll
    for (int ks = 0; ks < 2; ++ks) {
        half8 a0 = *(const half8*)(vt + tswb(w * 32 + l15,      ks * 4 + l16));
        half8 a1 = *(const half8*)(vt + tswb(w * 32 + 16 + l15, ks * 4 + l16));
#pragma unroll
        for (int fj = 0; fj < 8; ++fj) {
            half8 bf = *(const half8*)(kt + tswb(fj * 16 + l15, ks * 4 + l16));
            acc[0][fj] = __builtin_amdgcn_mfma_f32_16x16x32_f16(a0, bf, acc[0][fj], 0, 0, 0);
            acc[1][fj] = __builtin_amdgcn_mfma_f32_16x16x32_f16(a1, bf, acc[1][fj], 0, 0, 0);
        }
    }
    __syncthreads();

    _Float16* buf = sm;
#pragma unroll
    for (int fi = 0; fi < 2; ++fi)
#pragma unroll
        for (int fj = 0; fj < 8; ++fj)
#pragma unroll
            for (int r = 0; r < 4; ++r)
                buf[(w * 32 + fi * 16 + l16 * 4 + r) * 136 + fj * 16 + l15] =
                    (_Float16)acc[fi][fj][r];
    __syncthreads();

    _Float16* Ub = U + (((size_t)blockIdx.x) << 14);
#pragma unroll
    for (int rep = 0; rep < 8; ++rep) {
        int u = rep * 256 + tid;
        int i = u >> 4, jq = u & 15;
        *(half8*)(Ub + i * 128 + jq * 8) = *(const half8*)(buf + i * 136 + jq * 8);
    }
}

// ---------------------------------------------------------------------------
// R2: chunk-boundary state scan; 512 blocks x 128 threads, STATIC 2-deep
// prefetch (named n0/n1 — runtime-indexed buffers go to scratch, rule #20).
// Output Sst in FRAGMENT-ORDERED layout (see round-14 note).
// ---------------------------------------------------------------------------
__global__ __launch_bounds__(128) void r2_kernel(const _Float16* __restrict__ U,
                                                 _Float16* __restrict__ S,
                                                 const float* __restrict__ A_log)
{
    const int blk = blockIdx.x;
    const int bh = blk >> 4, part = blk & 15, h = bh & 15;
    const float decay = sigmoidf_(A_log[h]);
    const float d64 = __expf(64.0f * logf(decay));
    const int tid = threadIdx.x;
    const size_t base = ((size_t)bh << 19) + (size_t)part * 1024 + (size_t)tid * 8;
    const half8* Up = (const half8*)(U + base);

    const int v  = part * 8 + (tid >> 4);
    const int d0 = (tid & 15) * 8;
    const int nf = v >> 4, l15 = v & 15;
    const int kd = d0 >> 5, l16 = (d0 >> 3) & 3;
    half8* Sp = (half8*)(S + ((size_t)bh << 19) +
                         (size_t)(((nf * 4 + kd) * 64) + l16 * 16 + l15) * 8);

    float st[8] = {0, 0, 0, 0, 0, 0, 0, 0};
    half8 n0 = Up[0];
    half8 n1 = Up[2048];
    for (int c = 0; c < 32; ++c) {
        half8 cur = n0;
        n0 = n1;
        if (c + 2 < 32) n1 = Up[(size_t)(c + 2) * 2048];
        half8 so;
#pragma unroll
        for (int i = 0; i < 8; ++i) {
            so[i] = (_Float16)st[i];
            st[i] = d64 * st[i] + (float)cur[i];
        }
        Sp[(size_t)c * 2048] = so;
    }
}

// ---------------------------------------------------------------------------
// R3: out = mask(QK^T)V + rowscale(Q S^T), gated. Reads pre-conv'd kh/vh
// from r1; S fragments read coalesced from r2's fragment-ordered layout.
// ---------------------------------------------------------------------------
__global__ __launch_bounds__(256) void r3_kernel(const _Float16* __restrict__ pq,
                                                 const _Float16* __restrict__ kh,
                                                 const _Float16* __restrict__ vh,
                                                 const _Float16* __restrict__ S,
                                                 const _Float16* __restrict__ pg,
                                                 const float* __restrict__ qw,
                                                 const float* __restrict__ qb,
                                                 const float* __restrict__ A_log,
                                                 const float* __restrict__ beta,
                                                 _Float16* __restrict__ gated)
{
    const int c = blockIdx.x & 31, bh = blockIdx.x >> 5;
    const int h = bh & 15, b = bh >> 4;
    const float decay = sigmoidf_(A_log[h]);
    const float bet = sigmoidf_(beta[h]);
    const float ld = logf(decay);

    __shared__ _Float16 vt[128 * 72];       // [n][s] swizzled (tsw)
    __shared__ _Float16 kbuf[64 * 136];     // k; reused as out bounce
    __shared__ _Float16 qps[64 * 136];      // conv'd q; reused as masked-P
    __shared__ float e1[65];

    const int tid = threadIdx.x;
    if (tid < 65) e1[tid] = __expf(ld * (float)tid);

#pragma unroll
    for (int rep = 0; rep < 4; ++rep) {
        int s = rep * 16 + (tid >> 4);
        int nq = tid & 15;
        int t = c * 64 + s;
        int ch = h * 128 + nq * 8;
        size_t rb = ((size_t)(b * T_ + t)) * DIM_ + ch;
        half8 k8 = *(const half8*)(kh + rb);
        half8 v8 = *(const half8*)(vh + rb);
        float qa[8];
        conv8(pq, qw, qb, rb, t, ch, qa);
        half8 q8;
#pragma unroll
        for (int u = 0; u < 8; ++u) {
            float q = qa[u];
            q8[u] = (_Float16)(q * sigmoidf_(q));
            vt[tsw(nq * 8 + u, s)] = v8[u];
        }
        *(half8*)(kbuf + s * 136 + ((nq ^ (s & 7)) * 8)) = k8;
        *(half8*)(qps + s * 136 + ((nq ^ (s & 7)) * 8)) = q8;
    }
    __syncthreads();

    const int lane = tid & 63, w = tid >> 6;
    const int l15 = lane & 15, l16 = lane >> 4;
    const int qr = w * 16 + l15;

    half8 af[4];
#pragma unroll
    for (int kd = 0; kd < 4; ++kd)
        af[kd] = *(const half8*)(qps + qr * 136 + (((kd * 4 + l16) ^ (qr & 7)) * 8));
    __syncthreads();   // all waves hold Q in regs before qps is overwritten

    f32x4 pacc[4] = {};
#pragma unroll
    for (int sf = 0; sf < 4; ++sf) {
        int s = sf * 16 + l15;
#pragma unroll
        for (int kd = 0; kd < 4; ++kd) {
            half8 bf = *(const half8*)(kbuf + s * 136 + (((kd * 4 + l16) ^ (s & 7)) * 8));
            pacc[sf] = __builtin_amdgcn_mfma_f32_16x16x32_f16(af[kd], bf, pacc[sf], 0, 0, 0);
        }
    }
#pragma unroll
    for (int sf = 0; sf < 4; ++sf)
#pragma unroll
        for (int r = 0; r < 4; ++r) {
            int tl = w * 16 + l16 * 4 + r;
            int s = sf * 16 + l15;
            float f = (s <= tl) ? bet * e1[tl - s] : 0.0f;
            qps[tl * 72 + s] = (_Float16)(pacc[sf][r] * f);   // ps[tl][s]
        }
    __syncthreads();

    half8 pf[2];
#pragma unroll
    for (int ks = 0; ks < 2; ++ks)
        pf[ks] = *(const half8*)(qps + (w * 16 + l15) * 72 + ks * 32 + l16 * 8);

    f32x4 acc1[8] = {};
    f32x4 acc2[8] = {};
    const _Float16* Sb = S + (((size_t)blockIdx.x) << 14);
#pragma unroll
    for (int nf = 0; nf < 8; ++nf) {
#pragma unroll
        for (int kd = 0; kd < 4; ++kd) {
            half8 bf = *(const half8*)(Sb + (size_t)((nf * 4 + kd) * 64 + lane) * 8);
            acc1[nf] = __builtin_amdgcn_mfma_f32_16x16x32_f16(af[kd], bf, acc1[nf], 0, 0, 0);
        }
#pragma unroll
        for (int ks = 0; ks < 2; ++ks) {
            half8 bf = *(const half8*)(vt + tswb(nf * 16 + l15, ks * 4 + l16));
            acc2[nf] = __builtin_amdgcn_mfma_f32_16x16x32_f16(pf[ks], bf, acc2[nf], 0, 0, 0);
        }
    }
#pragma unroll
    for (int nf = 0; nf < 8; ++nf)
#pragma unroll
        for (int r = 0; r < 4; ++r) {
            int tl = w * 16 + l16 * 4 + r;
            float o = acc2[nf][r] + e1[tl + 1] * acc1[nf][r];
            kbuf[tl * 136 + nf * 16 + l15] = (_Float16)o;
        }
    __syncthreads();

#pragma unroll
    for (int rep = 0; rep < 4; ++rep) {
        int u = rep * 256 + tid;
        int tl = u >> 4, jq = u & 15;
        size_t row = (size_t)(b * T_ + c * 64 + tl);
        half8 o8 = *(const half8*)(kbuf + tl * 136 + jq * 8);
        half8 g8 = *(const half8*)(pg + row * DIM_ + h * 128 + jq * 8);
        half8 r8;
#pragma unroll
        for (int j = 0; j < 8; ++j)
            r8[j] = (_Float16)((float)o8[j] * sigmoidf_((float)g8[j]));
        *(half8*)(gated + row * DIM_ + h * 128 + jq * 8) = r8;
    }
}

// ---------------------------------------------------------------------------
extern "C" void kernel_launch(void* const* d_in, const int* in_sizes, int n_in,
                              void* d_out, int out_size, void* d_ws, size_t ws_size,
                              hipStream_t stream)
{
    const float* x     = (const float*)d_in[0];
    const float* Wq    = (const float*)d_in[1];
    const float* Wk    = (const float*)d_in[2];
    const float* Wv    = (const float*)d_in[3];
    const float* Wo    = (const float*)d_in[4];
    const float* Wg    = (const float*)d_in[5];
    const float* qw    = (const float*)d_in[6];
    const float* qb    = (const float*)d_in[7];
    const float* kw    = (const float*)d_in[8];
    const float* kb    = (const float*)d_in[9];
    const float* vw    = (const float*)d_in[10];
    const float* vb    = (const float*)d_in[11];
    const float* beta  = (const float*)d_in[12];
    const float* A_log = (const float*)d_in[13];
    float* out = (float*)d_out;

    char* wsb = (char*)d_ws;
    const size_t WT  = (size_t)DIM_ * DIM_ * 2;
    const size_t SZ  = (size_t)B_ * T_ * DIM_;
    const size_t SZH = SZ * 2;

    _Float16* wtq = (_Float16*)(wsb + 0 * WT);    // wtq..wtg contiguous = Bt[8192][2048]
    _Float16* wto = (_Float16*)(wsb + 4 * WT);
    char* pbase = wsb + 5 * WT;
    _Float16* pq = (_Float16*)(pbase + 0 * SZH);  // raw q projection (live to r3)
    _Float16* pk = (_Float16*)(pbase + 1 * SZH);  // raw k projection (dead after r1)
    _Float16* pv = (_Float16*)(pbase + 2 * SZH);  // raw v projection (dead after r1)
    _Float16* xh = (_Float16*)(pbase + 3 * SZH);  // dead after proj GEMM
    _Float16* pg = (_Float16*)(pbase + 4 * SZH);  // live to r3
    _Float16* U    = (_Float16*)(pbase + 5 * SZH);  // 32 MB (slots 5-6)
    _Float16* Sst  = (_Float16*)(pbase + 7 * SZH);  // 32 MB (slots 7-8)
    _Float16* kh   = xh;                            // conv'd k (xh dead)
    _Float16* vh   = (_Float16*)(pbase + 9 * SZH);  // conv'd v (new slot)
    _Float16* gated = U;                            // U dead after r2

    // cvt + 5 weight transposes in one launch (vectorized)
    prep<<<dim3(32, 32, 6), 256, 0, stream>>>(Wq, Wk, Wv, Wg, Wo, wtq, x, xh);

    // fused projections: M=4096, N=8192 (q|k|v|g): 16x32 = 512 tiles of 256^2
    gemm8ph<256><<<512, 512, 0, stream>>>(xh, wtq, pq, pk, pv, pg,
                                          DIM_, 32, 64);

    r1_kernel<<<B_ * H_ * 32, 256, 0, stream>>>(pk, pv, kw, kb, vw, vb,
                                                A_log, beta, U, kh, vh);
    r2_kernel<<<512, 128, 0, stream>>>(U, Sst, A_log);
    r3_kernel<<<B_ * H_ * 32, 256, 0, stream>>>(pq, kh, vh, Sst, pg,
                                                qw, qb, A_log, beta, gated);

    // out = gated @ Wo : M=4096, N=2048 -> 32x16 = 512 tiles of 128x128
    gemmp<128, float><<<512, 512, 0, stream>>>(gated, wto, out, out, out, out,
                                               DIM_, 16, 64);
}

// Round 17
// 324.536 us; speedup vs baseline: 1.4269x; 1.0141x over previous
//
#include <hip/hip_runtime.h>
#include <math.h>

#define B_   2
#define T_   2048
#define DIM_ 2048
#define H_   16

typedef __attribute__((ext_vector_type(8))) _Float16 half8;
typedef __attribute__((ext_vector_type(4))) float f32x4;

__device__ __forceinline__ float sigmoidf_(float x) { return 1.0f / (1.0f + __expf(-x)); }

__device__ __forceinline__ void gload16(const _Float16* g, _Float16* l) {
    __builtin_amdgcn_global_load_lds((const __attribute__((address_space(1))) void*)g,
                                     (__attribute__((address_space(3))) void*)l, 16, 0, 0);
}

#define VMW(n) asm volatile("s_waitcnt vmcnt(" #n ")" ::: "memory")

// Swizzled transpose-LDS addressing for [row][72] f16 tiles holding [row][s].
__device__ __forceinline__ int tsw(int row, int s) {
    return row * 72 + ((((s >> 3) ^ ((row >> 3) & 7)) << 3) | (s & 7));
}
__device__ __forceinline__ int tswb(int row, int sb) {
    return row * 72 + (((sb ^ ((row >> 3) & 7)) << 3));
}

// Depthwise causal conv K=4, 8 channels, fp32 math.
__device__ __forceinline__ void conv8(const _Float16* __restrict__ src,
                                      const float* __restrict__ w,
                                      const float* __restrict__ bias,
                                      size_t rb, int t, int ch, float* acc)
{
    float4 w4[8];
#pragma unroll
    for (int u = 0; u < 8; ++u) {
        w4[u] = *(const float4*)(w + (ch + u) * 4);
        acc[u] = bias[ch + u];
    }
#pragma unroll
    for (int j = 0; j < 4; ++j) {
        if (t - 3 + j >= 0) {
            half8 xv = *(const half8*)(src + rb + (ptrdiff_t)(j - 3) * DIM_);
#pragma unroll
            for (int u = 0; u < 8; ++u)
                acc[u] += (float)xv[u] * ((const float*)&w4[u])[j];
        }
    }
}

// ---------------------------------------------------------------------------
// prep: z<5 -> weight transpose W[K][N] f32 -> Wt[N][K] f16 (vectorized);
//       z==5 -> x f32->f16 cvt.
// ---------------------------------------------------------------------------
__global__ __launch_bounds__(256) void prep(const float* __restrict__ W0,
                                            const float* __restrict__ W1,
                                            const float* __restrict__ W2,
                                            const float* __restrict__ W3,
                                            const float* __restrict__ W4,
                                            _Float16* __restrict__ wbase,
                                            const float* __restrict__ x,
                                            _Float16* __restrict__ xh)
{
    const int z = blockIdx.z;
    if (z == 5) {
        size_t blk = ((size_t)blockIdx.y * 32 + blockIdx.x) * 8192;
#pragma unroll
        for (int j = 0; j < 4; ++j) {
            size_t i = blk + (size_t)j * 2048 + (size_t)threadIdx.x * 8;
            float4 a = *(const float4*)(x + i);
            float4 b = *(const float4*)(x + i + 4);
            half8 h;
            h[0] = (_Float16)a.x; h[1] = (_Float16)a.y; h[2] = (_Float16)a.z; h[3] = (_Float16)a.w;
            h[4] = (_Float16)b.x; h[5] = (_Float16)b.y; h[6] = (_Float16)b.z; h[7] = (_Float16)b.w;
            *(half8*)(xh + i) = h;
        }
        return;
    }
    __shared__ float t[64 * 65];
    const float* W = z == 0 ? W0 : z == 1 ? W1 : z == 2 ? W2 : z == 3 ? W3 : W4;
    _Float16* Wt = wbase + (size_t)z * DIM_ * DIM_;
    const int n0 = blockIdx.x * 64, k0 = blockIdx.y * 64;
#pragma unroll
    for (int rep = 0; rep < 4; ++rep) {
        int row = rep * 16 + (threadIdx.x >> 4);
        int qc = threadIdx.x & 15;
        float4 v = *(const float4*)(W + (size_t)(k0 + row) * DIM_ + n0 + qc * 4);
        t[row * 65 + qc * 4 + 0] = v.x;
        t[row * 65 + qc * 4 + 1] = v.y;
        t[row * 65 + qc * 4 + 2] = v.z;
        t[row * 65 + qc * 4 + 3] = v.w;
    }
    __syncthreads();
#pragma unroll
    for (int rep = 0; rep < 2; ++rep) {
        int r = rep * 32 + (threadIdx.x >> 3);
        int q = threadIdx.x & 7;
        half8 o;
#pragma unroll
        for (int j = 0; j < 8; ++j)
            o[j] = (_Float16)t[(q * 8 + j) * 65 + r];
        *(half8*)(Wt + (size_t)(n0 + r) * DIM_ + k0 + q * 8) = o;
    }
}

// ---------------------------------------------------------------------------
// 8-phase pipelined MFMA GEMM (measured-best on proj): 256x256 tile, BK=64,
// 2 K-tiles/iter, 8 waves (2M x 4N), counted vmcnt(4), 3-bit XOR swizzle.
// Epilogue: two-pass LDS bounce -> coalesced half8 stores.
// ---------------------------------------------------------------------------
template <int BM>
__global__ __launch_bounds__(512, 1) void gemm8ph(const _Float16* __restrict__ A,
                                                  const _Float16* __restrict__ Bt,
                                                  _Float16* __restrict__ C0, _Float16* __restrict__ C1,
                                                  _Float16* __restrict__ C2, _Float16* __restrict__ C3,
                                                  int K, int nx, int cpx)
{
    constexpr int MF  = BM / 32;
    constexpr int AQ  = MF / 4;
    constexpr int ASZ = BM * 64;
    constexpr int DSZ = (BM + 256) * 64;
    __shared__ _Float16 lds[2 * DSZ];

    const int tid = threadIdx.x;
    const int lane = tid & 63, w = tid >> 6;
    const int wr = w >> 2, wc = w & 3;
    const int l15 = lane & 15, l16 = lane >> 4;

    const int bid = blockIdx.x;
    const int swz = (bid & 7) * cpx + (bid >> 3);
    const int bm = (swz / nx) * BM, bn = (swz % nx) * 256;

    const int r0 = tid >> 3;
    const int c0 = ((tid & 7) ^ (r0 & 7)) * 8;
    const _Float16* Ab = A + (size_t)(bm + r0) * K + c0;
    const _Float16* Bb = Bt + (size_t)(bn + r0) * K + c0;

#define STAGE_A(d, kt) do { _Pragma("unroll")                                    \
    for (int u = 0; u < BM / 64; ++u)                                            \
        gload16(Ab + (size_t)(u * 64) * K + (size_t)(kt) * 64,                   \
                lds + (d) * DSZ + u * 4096 + tid * 8); } while (0)
#define STAGE_B(d, h, kt) do {                                                   \
    gload16(Bb + (size_t)((h) * 128) * K + (size_t)(kt) * 64,                    \
            lds + (d) * DSZ + ASZ + (h) * 8192 + tid * 8);                       \
    gload16(Bb + (size_t)((h) * 128 + 64) * K + (size_t)(kt) * 64,               \
            lds + (d) * DSZ + ASZ + (h) * 8192 + 4096 + tid * 8); } while (0)

    int aoff[MF][2], boff[4][2];
#pragma unroll
    for (int m = 0; m < MF; ++m) {
        int R = wr * (BM / 2) + m * 16 + l15;
#pragma unroll
        for (int ks = 0; ks < 2; ++ks)
            aoff[m][ks] = R * 64 + (((ks * 4 + l16) ^ (R & 7)) * 8);
    }
#pragma unroll
    for (int n = 0; n < 4; ++n) {
        int R = wc * 64 + n * 16 + l15;
#pragma unroll
        for (int ks = 0; ks < 2; ++ks)
            boff[n][ks] = ASZ + R * 64 + (((ks * 4 + l16) ^ (R & 7)) * 8);
    }

    f32x4 acc[MF][4] = {};
    half8 bfr[4][2];
    const int nj = K >> 7;

    STAGE_A(0, 0);
    STAGE_B(0, 0, 0); STAGE_B(0, 1, 0);
    STAGE_B(1, 0, 1); STAGE_B(1, 1, 1);
    VMW(4);
    __builtin_amdgcn_s_barrier();
    __builtin_amdgcn_sched_barrier(0);

#define PH(TT, Q, STAGECODE, VMCODE) do {                                        \
    const int dB_ = (TT) * DSZ;                                                  \
    half8 af_[AQ][2];                                                            \
    if ((Q) == 0) {                                                              \
        _Pragma("unroll") for (int n_ = 0; n_ < 4; ++n_)                         \
        _Pragma("unroll") for (int ks_ = 0; ks_ < 2; ++ks_)                      \
            bfr[n_][ks_] = *(const half8*)(lds + dB_ + boff[n_][ks_]);           \
    }                                                                            \
    _Pragma("unroll") for (int a_ = 0; a_ < AQ; ++a_)                            \
    _Pragma("unroll") for (int ks_ = 0; ks_ < 2; ++ks_)                          \
        af_[a_][ks_] = *(const half8*)(lds + dB_ + aoff[(Q) * AQ + a_][ks_]);    \
    STAGECODE;                                                                   \
    __builtin_amdgcn_s_barrier();                                                \
    asm volatile("s_waitcnt lgkmcnt(0)" ::: "memory");                           \
    __builtin_amdgcn_sched_barrier(0);                                           \
    __builtin_amdgcn_s_setprio(1);                                               \
    _Pragma("unroll") for (int ks_ = 0; ks_ < 2; ++ks_)                          \
    _Pragma("unroll") for (int a_ = 0; a_ < AQ; ++a_)                            \
    _Pragma("unroll") for (int n_ = 0; n_ < 4; ++n_)                             \
        acc[(Q) * AQ + a_][n_] = __builtin_amdgcn_mfma_f32_16x16x32_f16(         \
            af_[a_][ks_], bfr[n_][ks_], acc[(Q) * AQ + a_][n_], 0, 0, 0);        \
    __builtin_amdgcn_s_setprio(0);                                               \
    __builtin_amdgcn_sched_barrier(0);                                           \
    VMCODE;                                                                      \
    __builtin_amdgcn_s_barrier();                                                \
} while (0)

    for (int j = 0; j < nj; ++j) {
        const bool pf = (j + 1 < nj);
        const int t1 = 2 * j + 1, tn0 = 2 * j + 2, tn1 = 2 * j + 3;
        PH(0, 0, { STAGE_A(1, t1); }, {});
        PH(0, 1, { if (pf) STAGE_B(0, 0, tn0); }, {});
        PH(0, 2, { if (pf) STAGE_B(0, 1, tn0); }, {});
        PH(0, 3, {}, { if (pf) { VMW(4); } else { VMW(0); } });
        PH(1, 0, { if (pf) STAGE_A(0, tn0); }, {});
        PH(1, 1, {}, {});
        PH(1, 2, { if (pf) STAGE_B(1, 0, tn1); }, {});
        PH(1, 3, { if (pf) STAGE_B(1, 1, tn1); }, { if (pf) VMW(4); });
    }
#undef PH
#undef STAGE_A
#undef STAGE_B

    const int sel = bn >> 11;
    _Float16* __restrict__ C = sel == 0 ? C0 : sel == 1 ? C1 : sel == 2 ? C2 : C3;
    const int ccol0 = bn & 2047;
    _Float16* bb = lds;
#pragma unroll
    for (int p = 0; p < 2; ++p) {
        if (p) __syncthreads();
        if (wr == p) {
#pragma unroll
            for (int m = 0; m < MF; ++m)
#pragma unroll
                for (int n = 0; n < 4; ++n)
#pragma unroll
                    for (int r = 0; r < 4; ++r)
                        bb[(m * 16 + l16 * 4 + r) * 264 + wc * 64 + n * 16 + l15] =
                            (_Float16)acc[m][n][r];
        }
        __syncthreads();
#pragma unroll
        for (int rep = 0; rep < 8; ++rep) {
            int u = rep * 512 + tid;
            int i = u >> 5, q = u & 31;
            *(half8*)(C + (size_t)(bm + p * 128 + i) * 2048 + ccol0 + q * 8) =
                *(const half8*)(bb + i * 264 + q * 8);
        }
    }
}

// ---------------------------------------------------------------------------
// Occupancy-2 pipelined GEMM for the Wo matmul: 256x128, BK=32, 8 waves,
// 3 LDS buffers, counted vmcnt, verified swizzle, two-pass f32 bounce.
// (A/B across rounds 14/16: BM=256 beats BM=128 by ~5 us for this shape.)
// ---------------------------------------------------------------------------
template <int BM, typename OT>
__global__ __launch_bounds__(512, 4) void gemmp(const _Float16* __restrict__ A,
                                                const _Float16* __restrict__ Bt,
                                                OT* __restrict__ C0, OT* __restrict__ C1,
                                                OT* __restrict__ C2, OT* __restrict__ C3,
                                                int K, int nx, int cpx)
{
    static_assert(BM == 256, "two-pass epilogue assumes BM=256");
    constexpr int BN   = 128;
    constexpr int LPT  = (BM + BN) / 128;
    constexpr int WR   = BM / 4;
    constexpr int MF   = WR / 16;
    constexpr int ASZ  = BM * 32;
    constexpr int DSZ  = (BM + BN) * 32;
    __shared__ alignas(16) char ldsraw[3 * DSZ * 2];
    _Float16* lds = reinterpret_cast<_Float16*>(ldsraw);

    const int tid = threadIdx.x;
    const int lane = tid & 63, w = tid >> 6;
    const int wr = w >> 1, wc = w & 1;
    const int l15 = lane & 15, l16 = lane >> 4;

    const int bid = blockIdx.x;
    const int swz = (bid & 7) * cpx + (bid >> 3);
    const int bm = (swz / nx) * BM, bn = (swz % nx) * BN;

    const _Float16* src[LPT];
    int ldst[LPT];
#pragma unroll
    for (int ld = 0; ld < LPT; ++ld) {
        int F = ld * 512 + tid;
        int R = F >> 2;
        int sc = (F & 3) ^ (((R >> 3) & 1) << 1);
        src[ld] = (R < BM) ? A + (size_t)(bm + R) * K + sc * 8
                           : Bt + (size_t)(bn + R - BM) * K + sc * 8;
        ldst[ld] = F * 8;
    }

    int aoff[MF], boff[4];
#pragma unroll
    for (int m = 0; m < MF; ++m) {
        int R = wr * WR + m * 16 + l15;
        aoff[m] = R * 32 + ((l16 ^ (((R >> 3) & 1) << 1)) * 8);
    }
#pragma unroll
    for (int n = 0; n < 4; ++n) {
        int R = wc * 64 + n * 16 + l15;
        boff[n] = ASZ + R * 32 + ((l16 ^ (((R >> 3) & 1) << 1)) * 8);
    }

    f32x4 acc[MF][4] = {};
    const int nt = K >> 5;

#define STAGE(kt, buf) do { _Pragma("unroll")                                  \
    for (int ld_ = 0; ld_ < LPT; ++ld_)                                        \
        gload16(src[ld_] + (size_t)(kt) * 32, lds + (buf) * DSZ + ldst[ld_]);  \
    } while (0)

    STAGE(0, 0);
    STAGE(1, 1);
    VMW(3);
    __builtin_amdgcn_s_barrier();
    __builtin_amdgcn_sched_barrier(0);

    int cb = 0, nb = 2;
    for (int t = 0; t < nt; ++t) {
        const _Float16* L = lds + cb * DSZ;
        half8 af[MF], bf[4];
#pragma unroll
        for (int m = 0; m < MF; ++m) af[m] = *(const half8*)(L + aoff[m]);
#pragma unroll
        for (int n = 0; n < 4; ++n) bf[n] = *(const half8*)(L + boff[n]);

        const bool pf = (t + 2 < nt);
        if (pf) STAGE(t + 2, nb);

        asm volatile("s_waitcnt lgkmcnt(0)" ::: "memory");
        __builtin_amdgcn_sched_barrier(0);
        __builtin_amdgcn_s_setprio(1);
#pragma unroll
        for (int m = 0; m < MF; ++m)
#pragma unroll
            for (int n = 0; n < 4; ++n)
                acc[m][n] = __builtin_amdgcn_mfma_f32_16x16x32_f16(af[m], bf[n], acc[m][n], 0, 0, 0);
        __builtin_amdgcn_s_setprio(0);
        __builtin_amdgcn_sched_barrier(0);

        if (pf) VMW(3);
        else    VMW(0);
        __builtin_amdgcn_s_barrier();
        __builtin_amdgcn_sched_barrier(0);

        cb = (cb == 2) ? 0 : cb + 1;
        nb = (nb == 2) ? 0 : nb + 1;
    }
#undef STAGE

    const int sel = bn >> 11;
    OT* __restrict__ C = sel == 0 ? C0 : sel == 1 ? C1 : sel == 2 ? C2 : C3;
    const int ccol0 = bn & 2047;
    constexpr int VE = 16 / sizeof(OT);
    constexpr int CPR = 128 / VE;
    constexpr int BW = 128 + VE;
    OT* bb = reinterpret_cast<OT*>(ldsraw);
#pragma unroll
    for (int p = 0; p < 2; ++p) {
        if (p) __syncthreads();
        if ((wr >> 1) == p) {
            const int rb = (wr & 1) * 64;
#pragma unroll
            for (int m = 0; m < MF; ++m)
#pragma unroll
                for (int n = 0; n < 4; ++n)
#pragma unroll
                    for (int r = 0; r < 4; ++r)
                        bb[(rb + m * 16 + l16 * 4 + r) * BW + wc * 64 + n * 16 + l15] =
                            (OT)acc[m][n][r];
        }
        __syncthreads();
#pragma unroll
        for (int rep = 0; rep < (128 * CPR) / 512; ++rep) {
            int u = rep * 512 + tid;
            int i = u / CPR, q = u % CPR;
            if constexpr (sizeof(OT) == 2)
                *reinterpret_cast<half8*>(C + (size_t)(bm + p * 128 + i) * 2048 + ccol0 + q * VE) =
                    *reinterpret_cast<const half8*>(bb + i * BW + q * VE);
            else
                *reinterpret_cast<float4*>(C + (size_t)(bm + p * 128 + i) * 2048 + ccol0 + q * VE) =
                    *reinterpret_cast<const float4*>(bb + i * BW + q * VE);
        }
    }
}

// ---------------------------------------------------------------------------
// R1 (conv fused): per (bh, chunk) U_c = sum_s bet*decay^(63-s) v_s k_s^T.
// Also EXPORTS conv'd kh (normalized) and vh so r3 need not recompute them.
// ---------------------------------------------------------------------------
__global__ __launch_bounds__(256) void r1_kernel(const _Float16* __restrict__ pk,
                                                 const _Float16* __restrict__ pv,
                                                 const float* __restrict__ kw,
                                                 const float* __restrict__ kb,
                                                 const float* __restrict__ vw,
                                                 const float* __restrict__ vb,
                                                 const float* __restrict__ A_log,
                                                 const float* __restrict__ beta,
                                                 _Float16* __restrict__ U,
                                                 _Float16* __restrict__ kh,
                                                 _Float16* __restrict__ vh)
{
    const int c = blockIdx.x & 31, bh = blockIdx.x >> 5;
    const int h = bh & 15, b = bh >> 4;
    const float decay = sigmoidf_(A_log[h]);
    const float bet = sigmoidf_(beta[h]);
    const float ld = logf(decay);

    __shared__ _Float16 sm[2 * 128 * 72];
    _Float16* kt = sm;
    _Float16* vt = sm + 128 * 72;

    const int tid = threadIdx.x;

#pragma unroll
    for (int rep = 0; rep < 4; ++rep) {
        int s = rep * 16 + (tid >> 4);
        int dq = tid & 15;
        int t = c * 64 + s;
        int ch = h * 128 + dq * 8;
        size_t rb = ((size_t)(b * T_ + t)) * DIM_ + ch;
        float ka[8], va[8];
        conv8(pk, kw, kb, rb, t, ch, ka);
        conv8(pv, vw, vb, rb, t, ch, va);
        float ss = 0.0f;
#pragma unroll
        for (int u = 0; u < 8; ++u) {
            ka[u] = ka[u] * sigmoidf_(ka[u]);
            ss += ka[u] * ka[u];
        }
        ss += __shfl_xor(ss, 1);
        ss += __shfl_xor(ss, 2);
        ss += __shfl_xor(ss, 4);
        ss += __shfl_xor(ss, 8);
        float sc = 1.0f / fmaxf(sqrtf(ss), 1e-12f);
        float vsc = bet * __expf(ld * (float)(63 - s));
        half8 k8, v8;
#pragma unroll
        for (int u = 0; u < 8; ++u) {
            k8[u] = (_Float16)(ka[u] * sc);
            v8[u] = (_Float16)va[u];
            kt[tsw(dq * 8 + u, s)] = k8[u];
            vt[tsw(dq * 8 + u, s)] = (_Float16)(vsc * va[u]);
        }
        *(half8*)(kh + rb) = k8;   // export for r3 (identical rounding path)
        *(half8*)(vh + rb) = v8;
    }
    __syncthreads();

    const int lane = tid & 63, w = tid >> 6;
    const int l15 = lane & 15, l16 = lane >> 4;
    f32x4 acc[2][8] = {};
#pragma unroll
    for (int ks = 0; ks < 2; ++ks) {
        half8 a0 = *(const half8*)(vt + tswb(w * 32 + l15,      ks * 4 + l16));
        half8 a1 = *(const half8*)(vt + tswb(w * 32 + 16 + l15, ks * 4 + l16));
#pragma unroll
        for (int fj = 0; fj < 8; ++fj) {
            half8 bf = *(const half8*)(kt + tswb(fj * 16 + l15, ks * 4 + l16));
            acc[0][fj] = __builtin_amdgcn_mfma_f32_16x16x32_f16(a0, bf, acc[0][fj], 0, 0, 0);
            acc[1][fj] = __builtin_amdgcn_mfma_f32_16x16x32_f16(a1, bf, acc[1][fj], 0, 0, 0);
        }
    }
    __syncthreads();

    _Float16* buf = sm;
#pragma unroll
    for (int fi = 0; fi < 2; ++fi)
#pragma unroll
        for (int fj = 0; fj < 8; ++fj)
#pragma unroll
            for (int r = 0; r < 4; ++r)
                buf[(w * 32 + fi * 16 + l16 * 4 + r) * 136 + fj * 16 + l15] =
                    (_Float16)acc[fi][fj][r];
    __syncthreads();

    _Float16* Ub = U + (((size_t)blockIdx.x) << 14);
#pragma unroll
    for (int rep = 0; rep < 8; ++rep) {
        int u = rep * 256 + tid;
        int i = u >> 4, jq = u & 15;
        *(half8*)(Ub + i * 128 + jq * 8) = *(const half8*)(buf + i * 136 + jq * 8);
    }
}

// ---------------------------------------------------------------------------
// R2: chunk-boundary state scan; 512 blocks x 128 threads, STATIC 2-deep
// prefetch (named n0/n1). Output Sst in FRAGMENT-ORDERED layout.
// ---------------------------------------------------------------------------
__global__ __launch_bounds__(128) void r2_kernel(const _Float16* __restrict__ U,
                                                 _Float16* __restrict__ S,
                                                 const float* __restrict__ A_log)
{
    const int blk = blockIdx.x;
    const int bh = blk >> 4, part = blk & 15, h = bh & 15;
    const float decay = sigmoidf_(A_log[h]);
    const float d64 = __expf(64.0f * logf(decay));
    const int tid = threadIdx.x;
    const size_t base = ((size_t)bh << 19) + (size_t)part * 1024 + (size_t)tid * 8;
    const half8* Up = (const half8*)(U + base);

    const int v  = part * 8 + (tid >> 4);
    const int d0 = (tid & 15) * 8;
    const int nf = v >> 4, l15 = v & 15;
    const int kd = d0 >> 5, l16 = (d0 >> 3) & 3;
    half8* Sp = (half8*)(S + ((size_t)bh << 19) +
                         (size_t)(((nf * 4 + kd) * 64) + l16 * 16 + l15) * 8);

    float st[8] = {0, 0, 0, 0, 0, 0, 0, 0};
    half8 n0 = Up[0];
    half8 n1 = Up[2048];
    for (int c = 0; c < 32; ++c) {
        half8 cur = n0;
        n0 = n1;
        if (c + 2 < 32) n1 = Up[(size_t)(c + 2) * 2048];
        half8 so;
#pragma unroll
        for (int i = 0; i < 8; ++i) {
            so[i] = (_Float16)st[i];
            st[i] = d64 * st[i] + (float)cur[i];
        }
        Sp[(size_t)c * 2048] = so;
    }
}

// ---------------------------------------------------------------------------
// R3: out = mask(QK^T)V + rowscale(Q S^T), gated. Reads pre-conv'd kh/vh
// from r1; S fragments read coalesced from r2's fragment-ordered layout.
// ---------------------------------------------------------------------------
__global__ __launch_bounds__(256) void r3_kernel(const _Float16* __restrict__ pq,
                                                 const _Float16* __restrict__ kh,
                                                 const _Float16* __restrict__ vh,
                                                 const _Float16* __restrict__ S,
                                                 const _Float16* __restrict__ pg,
                                                 const float* __restrict__ qw,
                                                 const float* __restrict__ qb,
                                                 const float* __restrict__ A_log,
                                                 const float* __restrict__ beta,
                                                 _Float16* __restrict__ gated)
{
    const int c = blockIdx.x & 31, bh = blockIdx.x >> 5;
    const int h = bh & 15, b = bh >> 4;
    const float decay = sigmoidf_(A_log[h]);
    const float bet = sigmoidf_(beta[h]);
    const float ld = logf(decay);

    __shared__ _Float16 vt[128 * 72];       // [n][s] swizzled (tsw)
    __shared__ _Float16 kbuf[64 * 136];     // k; reused as out bounce
    __shared__ _Float16 qps[64 * 136];      // conv'd q; reused as masked-P
    __shared__ float e1[65];

    const int tid = threadIdx.x;
    if (tid < 65) e1[tid] = __expf(ld * (float)tid);

#pragma unroll
    for (int rep = 0; rep < 4; ++rep) {
        int s = rep * 16 + (tid >> 4);
        int nq = tid & 15;
        int t = c * 64 + s;
        int ch = h * 128 + nq * 8;
        size_t rb = ((size_t)(b * T_ + t)) * DIM_ + ch;
        half8 k8 = *(const half8*)(kh + rb);
        half8 v8 = *(const half8*)(vh + rb);
        float qa[8];
        conv8(pq, qw, qb, rb, t, ch, qa);
        half8 q8;
#pragma unroll
        for (int u = 0; u < 8; ++u) {
            float q = qa[u];
            q8[u] = (_Float16)(q * sigmoidf_(q));
            vt[tsw(nq * 8 + u, s)] = v8[u];
        }
        *(half8*)(kbuf + s * 136 + ((nq ^ (s & 7)) * 8)) = k8;
        *(half8*)(qps + s * 136 + ((nq ^ (s & 7)) * 8)) = q8;
    }
    __syncthreads();

    const int lane = tid & 63, w = tid >> 6;
    const int l15 = lane & 15, l16 = lane >> 4;
    const int qr = w * 16 + l15;

    half8 af[4];
#pragma unroll
    for (int kd = 0; kd < 4; ++kd)
        af[kd] = *(const half8*)(qps + qr * 136 + (((kd * 4 + l16) ^ (qr & 7)) * 8));
    __syncthreads();   // all waves hold Q in regs before qps is overwritten

    f32x4 pacc[4] = {};
#pragma unroll
    for (int sf = 0; sf < 4; ++sf) {
        int s = sf * 16 + l15;
#pragma unroll
        for (int kd = 0; kd < 4; ++kd) {
            half8 bf = *(const half8*)(kbuf + s * 136 + (((kd * 4 + l16) ^ (s & 7)) * 8));
            pacc[sf] = __builtin_amdgcn_mfma_f32_16x16x32_f16(af[kd], bf, pacc[sf], 0, 0, 0);
        }
    }
#pragma unroll
    for (int sf = 0; sf < 4; ++sf)
#pragma unroll
        for (int r = 0; r < 4; ++r) {
            int tl = w * 16 + l16 * 4 + r;
            int s = sf * 16 + l15;
            float f = (s <= tl) ? bet * e1[tl - s] : 0.0f;
            qps[tl * 72 + s] = (_Float16)(pacc[sf][r] * f);   // ps[tl][s]
        }
    __syncthreads();

    half8 pf[2];
#pragma unroll
    for (int ks = 0; ks < 2; ++ks)
        pf[ks] = *(const half8*)(qps + (w * 16 + l15) * 72 + ks * 32 + l16 * 8);

    f32x4 acc1[8] = {};
    f32x4 acc2[8] = {};
    const _Float16* Sb = S + (((size_t)blockIdx.x) << 14);
#pragma unroll
    for (int nf = 0; nf < 8; ++nf) {
#pragma unroll
        for (int kd = 0; kd < 4; ++kd) {
            half8 bf = *(const half8*)(Sb + (size_t)((nf * 4 + kd) * 64 + lane) * 8);
            acc1[nf] = __builtin_amdgcn_mfma_f32_16x16x32_f16(af[kd], bf, acc1[nf], 0, 0, 0);
        }
#pragma unroll
        for (int ks = 0; ks < 2; ++ks) {
            half8 bf = *(const half8*)(vt + tswb(nf * 16 + l15, ks * 4 + l16));
            acc2[nf] = __builtin_amdgcn_mfma_f32_16x16x32_f16(pf[ks], bf, acc2[nf], 0, 0, 0);
        }
    }
#pragma unroll
    for (int nf = 0; nf < 8; ++nf)
#pragma unroll
        for (int r = 0; r < 4; ++r) {
            int tl = w * 16 + l16 * 4 + r;
            float o = acc2[nf][r] + e1[tl + 1] * acc1[nf][r];
            kbuf[tl * 136 + nf * 16 + l15] = (_Float16)o;
        }
    __syncthreads();

#pragma unroll
    for (int rep = 0; rep < 4; ++rep) {
        int u = rep * 256 + tid;
        int tl = u >> 4, jq = u & 15;
        size_t row = (size_t)(b * T_ + c * 64 + tl);
        half8 o8 = *(const half8*)(kbuf + tl * 136 + jq * 8);
        half8 g8 = *(const half8*)(pg + row * DIM_ + h * 128 + jq * 8);
        half8 r8;
#pragma unroll
        for (int j = 0; j < 8; ++j)
            r8[j] = (_Float16)((float)o8[j] * sigmoidf_((float)g8[j]));
        *(half8*)(gated + row * DIM_ + h * 128 + jq * 8) = r8;
    }
}

// ---------------------------------------------------------------------------
extern "C" void kernel_launch(void* const* d_in, const int* in_sizes, int n_in,
                              void* d_out, int out_size, void* d_ws, size_t ws_size,
                              hipStream_t stream)
{
    const float* x     = (const float*)d_in[0];
    const float* Wq    = (const float*)d_in[1];
    const float* Wk    = (const float*)d_in[2];
    const float* Wv    = (const float*)d_in[3];
    const float* Wo    = (const float*)d_in[4];
    const float* Wg    = (const float*)d_in[5];
    const float* qw    = (const float*)d_in[6];
    const float* qb    = (const float*)d_in[7];
    const float* kw    = (const float*)d_in[8];
    const float* kb    = (const float*)d_in[9];
    const float* vw    = (const float*)d_in[10];
    const float* vb    = (const float*)d_in[11];
    const float* beta  = (const float*)d_in[12];
    const float* A_log = (const float*)d_in[13];
    float* out = (float*)d_out;

    char* wsb = (char*)d_ws;
    const size_t WT  = (size_t)DIM_ * DIM_ * 2;
    const size_t SZ  = (size_t)B_ * T_ * DIM_;
    const size_t SZH = SZ * 2;

    _Float16* wtq = (_Float16*)(wsb + 0 * WT);    // wtq..wtg contiguous = Bt[8192][2048]
    _Float16* wto = (_Float16*)(wsb + 4 * WT);
    char* pbase = wsb + 5 * WT;
    _Float16* pq = (_Float16*)(pbase + 0 * SZH);  // raw q projection (live to r3)
    _Float16* pk = (_Float16*)(pbase + 1 * SZH);  // raw k projection (dead after r1)
    _Float16* pv = (_Float16*)(pbase + 2 * SZH);  // raw v projection (dead after r1)
    _Float16* xh = (_Float16*)(pbase + 3 * SZH);  // dead after proj GEMM
    _Float16* pg = (_Float16*)(pbase + 4 * SZH);  // live to r3
    _Float16* U    = (_Float16*)(pbase + 5 * SZH);  // 32 MB (slots 5-6)
    _Float16* Sst  = (_Float16*)(pbase + 7 * SZH);  // 32 MB (slots 7-8)
    _Float16* kh   = xh;                            // conv'd k (xh dead)
    _Float16* vh   = (_Float16*)(pbase + 9 * SZH);  // conv'd v (new slot)
    _Float16* gated = U;                            // U dead after r2

    // cvt + 5 weight transposes in one launch (vectorized)
    prep<<<dim3(32, 32, 6), 256, 0, stream>>>(Wq, Wk, Wv, Wg, Wo, wtq, x, xh);

    // fused projections: M=4096, N=8192 (q|k|v|g): 16x32 = 512 tiles of 256^2
    gemm8ph<256><<<512, 512, 0, stream>>>(xh, wtq, pq, pk, pv, pg,
                                          DIM_, 32, 64);

    r1_kernel<<<B_ * H_ * 32, 256, 0, stream>>>(pk, pv, kw, kb, vw, vb,
                                                A_log, beta, U, kh, vh);
    r2_kernel<<<512, 128, 0, stream>>>(U, Sst, A_log);
    r3_kernel<<<B_ * H_ * 32, 256, 0, stream>>>(pq, kh, vh, Sst, pg,
                                                qw, qb, A_log, beta, gated);

    // out = gated @ Wo : M=4096, N=2048 -> 16x16 = 256 tiles of 256x128
    gemmp<256, float><<<256, 512, 0, stream>>>(gated, wto, out, out, out, out,
                                               DIM_, 16, 32);
}

// Round 18
// 320.102 us; speedup vs baseline: 1.4467x; 1.0139x over previous
//
#include <hip/hip_runtime.h>
#include <math.h>

#define B_   2
#define T_   2048
#define DIM_ 2048
#define H_   16

typedef __attribute__((ext_vector_type(8))) _Float16 half8;
typedef __attribute__((ext_vector_type(4))) float f32x4;

__device__ __forceinline__ float sigmoidf_(float x) { return 1.0f / (1.0f + __expf(-x)); }

__device__ __forceinline__ void gload16(const _Float16* g, _Float16* l) {
    __builtin_amdgcn_global_load_lds((const __attribute__((address_space(1))) void*)g,
                                     (__attribute__((address_space(3))) void*)l, 16, 0, 0);
}

#define VMW(n) asm volatile("s_waitcnt vmcnt(" #n ")" ::: "memory")

// Swizzled transpose-LDS addressing for [row][72] f16 tiles holding [row][s].
__device__ __forceinline__ int tsw(int row, int s) {
    return row * 72 + ((((s >> 3) ^ ((row >> 3) & 7)) << 3) | (s & 7));
}
__device__ __forceinline__ int tswb(int row, int sb) {
    return row * 72 + (((sb ^ ((row >> 3) & 7)) << 3));
}

// XCD-aware block remap, column-pair-major within each XCD chunk so
// consecutive blocks on one XCD share the same B-tile (L2 reuse).
// grid = (nwg/nx) rows x nx cols, chunk = cpx blocks = 2 rows x nx cols.
__device__ __forceinline__ void xcd_rc(int bid, int nx, int cpx, int* row, int* col) {
    int x = bid & 7, L = bid >> 3;
    *row = x * 2 + (L & 1);
    *col = L >> 1;
    (void)cpx;
}

// Depthwise causal conv K=4, 8 channels, fp32 math.
__device__ __forceinline__ void conv8(const _Float16* __restrict__ src,
                                      const float* __restrict__ w,
                                      const float* __restrict__ bias,
                                      size_t rb, int t, int ch, float* acc)
{
    float4 w4[8];
#pragma unroll
    for (int u = 0; u < 8; ++u) {
        w4[u] = *(const float4*)(w + (ch + u) * 4);
        acc[u] = bias[ch + u];
    }
#pragma unroll
    for (int j = 0; j < 4; ++j) {
        if (t - 3 + j >= 0) {
            half8 xv = *(const half8*)(src + rb + (ptrdiff_t)(j - 3) * DIM_);
#pragma unroll
            for (int u = 0; u < 8; ++u)
                acc[u] += (float)xv[u] * ((const float*)&w4[u])[j];
        }
    }
}

// ---------------------------------------------------------------------------
// prep: z<5 -> weight transpose W[K][N] f32 -> Wt[N][K] f16 (vectorized);
//       z==5 -> x f32->f16 cvt.
// ---------------------------------------------------------------------------
__global__ __launch_bounds__(256) void prep(const float* __restrict__ W0,
                                            const float* __restrict__ W1,
                                            const float* __restrict__ W2,
                                            const float* __restrict__ W3,
                                            const float* __restrict__ W4,
                                            _Float16* __restrict__ wbase,
                                            const float* __restrict__ x,
                                            _Float16* __restrict__ xh)
{
    const int z = blockIdx.z;
    if (z == 5) {
        size_t blk = ((size_t)blockIdx.y * 32 + blockIdx.x) * 8192;
#pragma unroll
        for (int j = 0; j < 4; ++j) {
            size_t i = blk + (size_t)j * 2048 + (size_t)threadIdx.x * 8;
            float4 a = *(const float4*)(x + i);
            float4 b = *(const float4*)(x + i + 4);
            half8 h;
            h[0] = (_Float16)a.x; h[1] = (_Float16)a.y; h[2] = (_Float16)a.z; h[3] = (_Float16)a.w;
            h[4] = (_Float16)b.x; h[5] = (_Float16)b.y; h[6] = (_Float16)b.z; h[7] = (_Float16)b.w;
            *(half8*)(xh + i) = h;
        }
        return;
    }
    __shared__ float t[64 * 65];
    const float* W = z == 0 ? W0 : z == 1 ? W1 : z == 2 ? W2 : z == 3 ? W3 : W4;
    _Float16* Wt = wbase + (size_t)z * DIM_ * DIM_;
    const int n0 = blockIdx.x * 64, k0 = blockIdx.y * 64;
#pragma unroll
    for (int rep = 0; rep < 4; ++rep) {
        int row = rep * 16 + (threadIdx.x >> 4);
        int qc = threadIdx.x & 15;
        float4 v = *(const float4*)(W + (size_t)(k0 + row) * DIM_ + n0 + qc * 4);
        t[row * 65 + qc * 4 + 0] = v.x;
        t[row * 65 + qc * 4 + 1] = v.y;
        t[row * 65 + qc * 4 + 2] = v.z;
        t[row * 65 + qc * 4 + 3] = v.w;
    }
    __syncthreads();
#pragma unroll
    for (int rep = 0; rep < 2; ++rep) {
        int r = rep * 32 + (threadIdx.x >> 3);
        int q = threadIdx.x & 7;
        half8 o;
#pragma unroll
        for (int j = 0; j < 8; ++j)
            o[j] = (_Float16)t[(q * 8 + j) * 65 + r];
        *(half8*)(Wt + (size_t)(n0 + r) * DIM_ + k0 + q * 8) = o;
    }
}

// ---------------------------------------------------------------------------
// 8-phase pipelined MFMA GEMM (measured-best on proj): 256x256 tile, BK=64,
// 2 K-tiles/iter, 8 waves (2M x 4N), counted vmcnt(4), 3-bit XOR swizzle.
// Epilogue: two-pass LDS bounce -> coalesced half8 stores.
// ---------------------------------------------------------------------------
template <int BM>
__global__ __launch_bounds__(512, 1) void gemm8ph(const _Float16* __restrict__ A,
                                                  const _Float16* __restrict__ Bt,
                                                  _Float16* __restrict__ C0, _Float16* __restrict__ C1,
                                                  _Float16* __restrict__ C2, _Float16* __restrict__ C3,
                                                  int K, int nx, int cpx)
{
    constexpr int MF  = BM / 32;
    constexpr int AQ  = MF / 4;
    constexpr int ASZ = BM * 64;
    constexpr int DSZ = (BM + 256) * 64;
    __shared__ _Float16 lds[2 * DSZ];

    const int tid = threadIdx.x;
    const int lane = tid & 63, w = tid >> 6;
    const int wr = w >> 2, wc = w & 3;
    const int l15 = lane & 15, l16 = lane >> 4;

    int brow, bcol;
    xcd_rc(blockIdx.x, nx, cpx, &brow, &bcol);
    const int bm = brow * BM, bn = bcol * 256;

    const int r0 = tid >> 3;
    const int c0 = ((tid & 7) ^ (r0 & 7)) * 8;
    const _Float16* Ab = A + (size_t)(bm + r0) * K + c0;
    const _Float16* Bb = Bt + (size_t)(bn + r0) * K + c0;

#define STAGE_A(d, kt) do { _Pragma("unroll")                                    \
    for (int u = 0; u < BM / 64; ++u)                                            \
        gload16(Ab + (size_t)(u * 64) * K + (size_t)(kt) * 64,                   \
                lds + (d) * DSZ + u * 4096 + tid * 8); } while (0)
#define STAGE_B(d, h, kt) do {                                                   \
    gload16(Bb + (size_t)((h) * 128) * K + (size_t)(kt) * 64,                    \
            lds + (d) * DSZ + ASZ + (h) * 8192 + tid * 8);                       \
    gload16(Bb + (size_t)((h) * 128 + 64) * K + (size_t)(kt) * 64,               \
            lds + (d) * DSZ + ASZ + (h) * 8192 + 4096 + tid * 8); } while (0)

    int aoff[MF][2], boff[4][2];
#pragma unroll
    for (int m = 0; m < MF; ++m) {
        int R = wr * (BM / 2) + m * 16 + l15;
#pragma unroll
        for (int ks = 0; ks < 2; ++ks)
            aoff[m][ks] = R * 64 + (((ks * 4 + l16) ^ (R & 7)) * 8);
    }
#pragma unroll
    for (int n = 0; n < 4; ++n) {
        int R = wc * 64 + n * 16 + l15;
#pragma unroll
        for (int ks = 0; ks < 2; ++ks)
            boff[n][ks] = ASZ + R * 64 + (((ks * 4 + l16) ^ (R & 7)) * 8);
    }

    f32x4 acc[MF][4] = {};
    half8 bfr[4][2];
    const int nj = K >> 7;

    STAGE_A(0, 0);
    STAGE_B(0, 0, 0); STAGE_B(0, 1, 0);
    STAGE_B(1, 0, 1); STAGE_B(1, 1, 1);
    VMW(4);
    __builtin_amdgcn_s_barrier();
    __builtin_amdgcn_sched_barrier(0);

#define PH(TT, Q, STAGECODE, VMCODE) do {                                        \
    const int dB_ = (TT) * DSZ;                                                  \
    half8 af_[AQ][2];                                                            \
    if ((Q) == 0) {                                                              \
        _Pragma("unroll") for (int n_ = 0; n_ < 4; ++n_)                         \
        _Pragma("unroll") for (int ks_ = 0; ks_ < 2; ++ks_)                      \
            bfr[n_][ks_] = *(const half8*)(lds + dB_ + boff[n_][ks_]);           \
    }                                                                            \
    _Pragma("unroll") for (int a_ = 0; a_ < AQ; ++a_)                            \
    _Pragma("unroll") for (int ks_ = 0; ks_ < 2; ++ks_)                          \
        af_[a_][ks_] = *(const half8*)(lds + dB_ + aoff[(Q) * AQ + a_][ks_]);    \
    STAGECODE;                                                                   \
    __builtin_amdgcn_s_barrier();                                                \
    asm volatile("s_waitcnt lgkmcnt(0)" ::: "memory");                           \
    __builtin_amdgcn_sched_barrier(0);                                           \
    __builtin_amdgcn_s_setprio(1);                                               \
    _Pragma("unroll") for (int ks_ = 0; ks_ < 2; ++ks_)                          \
    _Pragma("unroll") for (int a_ = 0; a_ < AQ; ++a_)                            \
    _Pragma("unroll") for (int n_ = 0; n_ < 4; ++n_)                             \
        acc[(Q) * AQ + a_][n_] = __builtin_amdgcn_mfma_f32_16x16x32_f16(         \
            af_[a_][ks_], bfr[n_][ks_], acc[(Q) * AQ + a_][n_], 0, 0, 0);        \
    __builtin_amdgcn_s_setprio(0);                                               \
    __builtin_amdgcn_sched_barrier(0);                                           \
    VMCODE;                                                                      \
    __builtin_amdgcn_s_barrier();                                                \
} while (0)

    for (int j = 0; j < nj; ++j) {
        const bool pf = (j + 1 < nj);
        const int t1 = 2 * j + 1, tn0 = 2 * j + 2, tn1 = 2 * j + 3;
        PH(0, 0, { STAGE_A(1, t1); }, {});
        PH(0, 1, { if (pf) STAGE_B(0, 0, tn0); }, {});
        PH(0, 2, { if (pf) STAGE_B(0, 1, tn0); }, {});
        PH(0, 3, {}, { if (pf) { VMW(4); } else { VMW(0); } });
        PH(1, 0, { if (pf) STAGE_A(0, tn0); }, {});
        PH(1, 1, {}, {});
        PH(1, 2, { if (pf) STAGE_B(1, 0, tn1); }, {});
        PH(1, 3, { if (pf) STAGE_B(1, 1, tn1); }, { if (pf) VMW(4); });
    }
#undef PH
#undef STAGE_A
#undef STAGE_B

    const int sel = bn >> 11;
    _Float16* __restrict__ C = sel == 0 ? C0 : sel == 1 ? C1 : sel == 2 ? C2 : C3;
    const int ccol0 = bn & 2047;
    _Float16* bb = lds;
#pragma unroll
    for (int p = 0; p < 2; ++p) {
        if (p) __syncthreads();
        if (wr == p) {
#pragma unroll
            for (int m = 0; m < MF; ++m)
#pragma unroll
                for (int n = 0; n < 4; ++n)
#pragma unroll
                    for (int r = 0; r < 4; ++r)
                        bb[(m * 16 + l16 * 4 + r) * 264 + wc * 64 + n * 16 + l15] =
                            (_Float16)acc[m][n][r];
        }
        __syncthreads();
#pragma unroll
        for (int rep = 0; rep < 8; ++rep) {
            int u = rep * 512 + tid;
            int i = u >> 5, q = u & 31;
            *(half8*)(C + (size_t)(bm + p * 128 + i) * 2048 + ccol0 + q * 8) =
                *(const half8*)(bb + i * 264 + q * 8);
        }
    }
}

// ---------------------------------------------------------------------------
// Occupancy-2 pipelined GEMM for the Wo matmul: 256x128, BK=32, 8 waves,
// 3 LDS buffers, counted vmcnt, verified swizzle, two-pass f32 bounce.
// ---------------------------------------------------------------------------
template <int BM, typename OT>
__global__ __launch_bounds__(512, 4) void gemmp(const _Float16* __restrict__ A,
                                                const _Float16* __restrict__ Bt,
                                                OT* __restrict__ C0, OT* __restrict__ C1,
                                                OT* __restrict__ C2, OT* __restrict__ C3,
                                                int K, int nx, int cpx)
{
    static_assert(BM == 256, "two-pass epilogue assumes BM=256");
    constexpr int BN   = 128;
    constexpr int LPT  = (BM + BN) / 128;
    constexpr int WR   = BM / 4;
    constexpr int MF   = WR / 16;
    constexpr int ASZ  = BM * 32;
    constexpr int DSZ  = (BM + BN) * 32;
    __shared__ alignas(16) char ldsraw[3 * DSZ * 2];
    _Float16* lds = reinterpret_cast<_Float16*>(ldsraw);

    const int tid = threadIdx.x;
    const int lane = tid & 63, w = tid >> 6;
    const int wr = w >> 1, wc = w & 1;
    const int l15 = lane & 15, l16 = lane >> 4;

    int brow, bcol;
    xcd_rc(blockIdx.x, nx, cpx, &brow, &bcol);
    const int bm = brow * BM, bn = bcol * BN;

    const _Float16* src[LPT];
    int ldst[LPT];
#pragma unroll
    for (int ld = 0; ld < LPT; ++ld) {
        int F = ld * 512 + tid;
        int R = F >> 2;
        int sc = (F & 3) ^ (((R >> 3) & 1) << 1);
        src[ld] = (R < BM) ? A + (size_t)(bm + R) * K + sc * 8
                           : Bt + (size_t)(bn + R - BM) * K + sc * 8;
        ldst[ld] = F * 8;
    }

    int aoff[MF], boff[4];
#pragma unroll
    for (int m = 0; m < MF; ++m) {
        int R = wr * WR + m * 16 + l15;
        aoff[m] = R * 32 + ((l16 ^ (((R >> 3) & 1) << 1)) * 8);
    }
#pragma unroll
    for (int n = 0; n < 4; ++n) {
        int R = wc * 64 + n * 16 + l15;
        boff[n] = ASZ + R * 32 + ((l16 ^ (((R >> 3) & 1) << 1)) * 8);
    }

    f32x4 acc[MF][4] = {};
    const int nt = K >> 5;

#define STAGE(kt, buf) do { _Pragma("unroll")                                  \
    for (int ld_ = 0; ld_ < LPT; ++ld_)                                        \
        gload16(src[ld_] + (size_t)(kt) * 32, lds + (buf) * DSZ + ldst[ld_]);  \
    } while (0)

    STAGE(0, 0);
    STAGE(1, 1);
    VMW(3);
    __builtin_amdgcn_s_barrier();
    __builtin_amdgcn_sched_barrier(0);

    int cb = 0, nb = 2;
    for (int t = 0; t < nt; ++t) {
        const _Float16* L = lds + cb * DSZ;
        half8 af[MF], bf[4];
#pragma unroll
        for (int m = 0; m < MF; ++m) af[m] = *(const half8*)(L + aoff[m]);
#pragma unroll
        for (int n = 0; n < 4; ++n) bf[n] = *(const half8*)(L + boff[n]);

        const bool pf = (t + 2 < nt);
        if (pf) STAGE(t + 2, nb);

        asm volatile("s_waitcnt lgkmcnt(0)" ::: "memory");
        __builtin_amdgcn_sched_barrier(0);
        __builtin_amdgcn_s_setprio(1);
#pragma unroll
        for (int m = 0; m < MF; ++m)
#pragma unroll
            for (int n = 0; n < 4; ++n)
                acc[m][n] = __builtin_amdgcn_mfma_f32_16x16x32_f16(af[m], bf[n], acc[m][n], 0, 0, 0);
        __builtin_amdgcn_s_setprio(0);
        __builtin_amdgcn_sched_barrier(0);

        if (pf) VMW(3);
        else    VMW(0);
        __builtin_amdgcn_s_barrier();
        __builtin_amdgcn_sched_barrier(0);

        cb = (cb == 2) ? 0 : cb + 1;
        nb = (nb == 2) ? 0 : nb + 1;
    }
#undef STAGE

    const int sel = bn >> 11;
    OT* __restrict__ C = sel == 0 ? C0 : sel == 1 ? C1 : sel == 2 ? C2 : C3;
    const int ccol0 = bn & 2047;
    constexpr int VE = 16 / sizeof(OT);
    constexpr int CPR = 128 / VE;
    constexpr int BW = 128 + VE;
    OT* bb = reinterpret_cast<OT*>(ldsraw);
#pragma unroll
    for (int p = 0; p < 2; ++p) {
        if (p) __syncthreads();
        if ((wr >> 1) == p) {
            const int rb = (wr & 1) * 64;
#pragma unroll
            for (int m = 0; m < MF; ++m)
#pragma unroll
                for (int n = 0; n < 4; ++n)
#pragma unroll
                    for (int r = 0; r < 4; ++r)
                        bb[(rb + m * 16 + l16 * 4 + r) * BW + wc * 64 + n * 16 + l15] =
                            (OT)acc[m][n][r];
        }
        __syncthreads();
#pragma unroll
        for (int rep = 0; rep < (128 * CPR) / 512; ++rep) {
            int u = rep * 512 + tid;
            int i = u / CPR, q = u % CPR;
            if constexpr (sizeof(OT) == 2)
                *reinterpret_cast<half8*>(C + (size_t)(bm + p * 128 + i) * 2048 + ccol0 + q * VE) =
                    *reinterpret_cast<const half8*>(bb + i * BW + q * VE);
            else
                *reinterpret_cast<float4*>(C + (size_t)(bm + p * 128 + i) * 2048 + ccol0 + q * VE) =
                    *reinterpret_cast<const float4*>(bb + i * BW + q * VE);
        }
    }
}

// ---------------------------------------------------------------------------
// R1 (conv fused): per (bh, chunk) U_c = sum_s bet*decay^(63-s) v_s k_s^T.
// Also EXPORTS conv'd kh (normalized) and vh so r3 need not recompute them.
// ---------------------------------------------------------------------------
__global__ __launch_bounds__(256) void r1_kernel(const _Float16* __restrict__ pk,
                                                 const _Float16* __restrict__ pv,
                                                 const float* __restrict__ kw,
                                                 const float* __restrict__ kb,
                                                 const float* __restrict__ vw,
                                                 const float* __restrict__ vb,
                                                 const float* __restrict__ A_log,
                                                 const float* __restrict__ beta,
                                                 _Float16* __restrict__ U,
                                                 _Float16* __restrict__ kh,
                                                 _Float16* __restrict__ vh)
{
    const int c = blockIdx.x & 31, bh = blockIdx.x >> 5;
    const int h = bh & 15, b = bh >> 4;
    const float decay = sigmoidf_(A_log[h]);
    const float bet = sigmoidf_(beta[h]);
    const float ld = logf(decay);

    __shared__ _Float16 sm[2 * 128 * 72];
    _Float16* kt = sm;
    _Float16* vt = sm + 128 * 72;

    const int tid = threadIdx.x;

#pragma unroll
    for (int rep = 0; rep < 4; ++rep) {
        int s = rep * 16 + (tid >> 4);
        int dq = tid & 15;
        int t = c * 64 + s;
        int ch = h * 128 + dq * 8;
        size_t rb = ((size_t)(b * T_ + t)) * DIM_ + ch;
        float ka[8], va[8];
        conv8(pk, kw, kb, rb, t, ch, ka);
        conv8(pv, vw, vb, rb, t, ch, va);
        float ss = 0.0f;
#pragma unroll
        for (int u = 0; u < 8; ++u) {
            ka[u] = ka[u] * sigmoidf_(ka[u]);
            ss += ka[u] * ka[u];
        }
        ss += __shfl_xor(ss, 1);
        ss += __shfl_xor(ss, 2);
        ss += __shfl_xor(ss, 4);
        ss += __shfl_xor(ss, 8);
        float sc = 1.0f / fmaxf(sqrtf(ss), 1e-12f);
        float vsc = bet * __expf(ld * (float)(63 - s));
        half8 k8, v8;
#pragma unroll
        for (int u = 0; u < 8; ++u) {
            k8[u] = (_Float16)(ka[u] * sc);
            v8[u] = (_Float16)va[u];
            kt[tsw(dq * 8 + u, s)] = k8[u];
            vt[tsw(dq * 8 + u, s)] = (_Float16)(vsc * va[u]);
        }
        *(half8*)(kh + rb) = k8;   // export for r3 (identical rounding path)
        *(half8*)(vh + rb) = v8;
    }
    __syncthreads();

    const int lane = tid & 63, w = tid >> 6;
    const int l15 = lane & 15, l16 = lane >> 4;
    f32x4 acc[2][8] = {};
#pragma unroll
    for (int ks = 0; ks < 2; ++ks) {
        half8 a0 = *(const half8*)(vt + tswb(w * 32 + l15,      ks * 4 + l16));
        half8 a1 = *(const half8*)(vt + tswb(w * 32 + 16 + l15, ks * 4 + l16));
#pragma unroll
        for (int fj = 0; fj < 8; ++fj) {
            half8 bf = *(const half8*)(kt + tswb(fj * 16 + l15, ks * 4 + l16));
            acc[0][fj] = __builtin_amdgcn_mfma_f32_16x16x32_f16(a0, bf, acc[0][fj], 0, 0, 0);
            acc[1][fj] = __builtin_amdgcn_mfma_f32_16x16x32_f16(a1, bf, acc[1][fj], 0, 0, 0);
        }
    }
    __syncthreads();

    _Float16* buf = sm;
#pragma unroll
    for (int fi = 0; fi < 2; ++fi)
#pragma unroll
        for (int fj = 0; fj < 8; ++fj)
#pragma unroll
            for (int r = 0; r < 4; ++r)
                buf[(w * 32 + fi * 16 + l16 * 4 + r) * 136 + fj * 16 + l15] =
                    (_Float16)acc[fi][fj][r];
    __syncthreads();

    _Float16* Ub = U + (((size_t)blockIdx.x) << 14);
#pragma unroll
    for (int rep = 0; rep < 8; ++rep) {
        int u = rep * 256 + tid;
        int i = u >> 4, jq = u & 15;
        *(half8*)(Ub + i * 128 + jq * 8) = *(const half8*)(buf + i * 136 + jq * 8);
    }
}

// ---------------------------------------------------------------------------
// R2: chunk-boundary state scan; 512 blocks x 128 threads, STATIC 2-deep
// prefetch (named n0/n1). Output Sst in FRAGMENT-ORDERED layout.
// ---------------------------------------------------------------------------
__global__ __launch_bounds__(128) void r2_kernel(const _Float16* __restrict__ U,
                                                 _Float16* __restrict__ S,
                                                 const float* __restrict__ A_log)
{
    const int blk = blockIdx.x;
    const int bh = blk >> 4, part = blk & 15, h = bh & 15;
    const float decay = sigmoidf_(A_log[h]);
    const float d64 = __expf(64.0f * logf(decay));
    const int tid = threadIdx.x;
    const size_t base = ((size_t)bh << 19) + (size_t)part * 1024 + (size_t)tid * 8;
    const half8* Up = (const half8*)(U + base);

    const int v  = part * 8 + (tid >> 4);
    const int d0 = (tid & 15) * 8;
    const int nf = v >> 4, l15 = v & 15;
    const int kd = d0 >> 5, l16 = (d0 >> 3) & 3;
    half8* Sp = (half8*)(S + ((size_t)bh << 19) +
                         (size_t)(((nf * 4 + kd) * 64) + l16 * 16 + l15) * 8);

    float st[8] = {0, 0, 0, 0, 0, 0, 0, 0};
    half8 n0 = Up[0];
    half8 n1 = Up[2048];
    for (int c = 0; c < 32; ++c) {
        half8 cur = n0;
        n0 = n1;
        if (c + 2 < 32) n1 = Up[(size_t)(c + 2) * 2048];
        half8 so;
#pragma unroll
        for (int i = 0; i < 8; ++i) {
            so[i] = (_Float16)st[i];
            st[i] = d64 * st[i] + (float)cur[i];
        }
        Sp[(size_t)c * 2048] = so;
    }
}

// ---------------------------------------------------------------------------
// R3: out = mask(QK^T)V + rowscale(Q S^T), gated. Reads pre-conv'd kh/vh
// from r1; S fragments read coalesced from r2's fragment-ordered layout.
// ---------------------------------------------------------------------------
__global__ __launch_bounds__(256) void r3_kernel(const _Float16* __restrict__ pq,
                                                 const _Float16* __restrict__ kh,
                                                 const _Float16* __restrict__ vh,
                                                 const _Float16* __restrict__ S,
                                                 const _Float16* __restrict__ pg,
                                                 const float* __restrict__ qw,
                                                 const float* __restrict__ qb,
                                                 const float* __restrict__ A_log,
                                                 const float* __restrict__ beta,
                                                 _Float16* __restrict__ gated)
{
    const int c = blockIdx.x & 31, bh = blockIdx.x >> 5;
    const int h = bh & 15, b = bh >> 4;
    const float decay = sigmoidf_(A_log[h]);
    const float bet = sigmoidf_(beta[h]);
    const float ld = logf(decay);

    __shared__ _Float16 vt[128 * 72];       // [n][s] swizzled (tsw)
    __shared__ _Float16 kbuf[64 * 136];     // k; reused as out bounce
    __shared__ _Float16 qps[64 * 136];      // conv'd q; reused as masked-P
    __shared__ float e1[65];

    const int tid = threadIdx.x;
    if (tid < 65) e1[tid] = __expf(ld * (float)tid);

#pragma unroll
    for (int rep = 0; rep < 4; ++rep) {
        int s = rep * 16 + (tid >> 4);
        int nq = tid & 15;
        int t = c * 64 + s;
        int ch = h * 128 + nq * 8;
        size_t rb = ((size_t)(b * T_ + t)) * DIM_ + ch;
        half8 k8 = *(const half8*)(kh + rb);
        half8 v8 = *(const half8*)(vh + rb);
        float qa[8];
        conv8(pq, qw, qb, rb, t, ch, qa);
        half8 q8;
#pragma unroll
        for (int u = 0; u < 8; ++u) {
            float q = qa[u];
            q8[u] = (_Float16)(q * sigmoidf_(q));
            vt[tsw(nq * 8 + u, s)] = v8[u];
        }
        *(half8*)(kbuf + s * 136 + ((nq ^ (s & 7)) * 8)) = k8;
        *(half8*)(qps + s * 136 + ((nq ^ (s & 7)) * 8)) = q8;
    }
    __syncthreads();

    const int lane = tid & 63, w = tid >> 6;
    const int l15 = lane & 15, l16 = lane >> 4;
    const int qr = w * 16 + l15;

    half8 af[4];
#pragma unroll
    for (int kd = 0; kd < 4; ++kd)
        af[kd] = *(const half8*)(qps + qr * 136 + (((kd * 4 + l16) ^ (qr & 7)) * 8));
    __syncthreads();   // all waves hold Q in regs before qps is overwritten

    f32x4 pacc[4] = {};
#pragma unroll
    for (int sf = 0; sf < 4; ++sf) {
        int s = sf * 16 + l15;
#pragma unroll
        for (int kd = 0; kd < 4; ++kd) {
            half8 bf = *(const half8*)(kbuf + s * 136 + (((kd * 4 + l16) ^ (s & 7)) * 8));
            pacc[sf] = __builtin_amdgcn_mfma_f32_16x16x32_f16(af[kd], bf, pacc[sf], 0, 0, 0);
        }
    }
#pragma unroll
    for (int sf = 0; sf < 4; ++sf)
#pragma unroll
        for (int r = 0; r < 4; ++r) {
            int tl = w * 16 + l16 * 4 + r;
            int s = sf * 16 + l15;
            float f = (s <= tl) ? bet * e1[tl - s] : 0.0f;
            qps[tl * 72 + s] = (_Float16)(pacc[sf][r] * f);   // ps[tl][s]
        }
    __syncthreads();

    half8 pf[2];
#pragma unroll
    for (int ks = 0; ks < 2; ++ks)
        pf[ks] = *(const half8*)(qps + (w * 16 + l15) * 72 + ks * 32 + l16 * 8);

    f32x4 acc1[8] = {};
    f32x4 acc2[8] = {};
    const _Float16* Sb = S + (((size_t)blockIdx.x) << 14);
#pragma unroll
    for (int nf = 0; nf < 8; ++nf) {
#pragma unroll
        for (int kd = 0; kd < 4; ++kd) {
            half8 bf = *(const half8*)(Sb + (size_t)((nf * 4 + kd) * 64 + lane) * 8);
            acc1[nf] = __builtin_amdgcn_mfma_f32_16x16x32_f16(af[kd], bf, acc1[nf], 0, 0, 0);
        }
#pragma unroll
        for (int ks = 0; ks < 2; ++ks) {
            half8 bf = *(const half8*)(vt + tswb(nf * 16 + l15, ks * 4 + l16));
            acc2[nf] = __builtin_amdgcn_mfma_f32_16x16x32_f16(pf[ks], bf, acc2[nf], 0, 0, 0);
        }
    }
#pragma unroll
    for (int nf = 0; nf < 8; ++nf)
#pragma unroll
        for (int r = 0; r < 4; ++r) {
            int tl = w * 16 + l16 * 4 + r;
            float o = acc2[nf][r] + e1[tl + 1] * acc1[nf][r];
            kbuf[tl * 136 + nf * 16 + l15] = (_Float16)o;
        }
    __syncthreads();

#pragma unroll
    for (int rep = 0; rep < 4; ++rep) {
        int u = rep * 256 + tid;
        int tl = u >> 4, jq = u & 15;
        size_t row = (size_t)(b * T_ + c * 64 + tl);
        half8 o8 = *(const half8*)(kbuf + tl * 136 + jq * 8);
        half8 g8 = *(const half8*)(pg + row * DIM_ + h * 128 + jq * 8);
        half8 r8;
#pragma unroll
        for (int j = 0; j < 8; ++j)
            r8[j] = (_Float16)((float)o8[j] * sigmoidf_((float)g8[j]));
        *(half8*)(gated + row * DIM_ + h * 128 + jq * 8) = r8;
    }
}

// ---------------------------------------------------------------------------
extern "C" void kernel_launch(void* const* d_in, const int* in_sizes, int n_in,
                              void* d_out, int out_size, void* d_ws, size_t ws_size,
                              hipStream_t stream)
{
    const float* x     = (const float*)d_in[0];
    const float* Wq    = (const float*)d_in[1];
    const float* Wk    = (const float*)d_in[2];
    const float* Wv    = (const float*)d_in[3];
    const float* Wo    = (const float*)d_in[4];
    const float* Wg    = (const float*)d_in[5];
    const float* qw    = (const float*)d_in[6];
    const float* qb    = (const float*)d_in[7];
    const float* kw    = (const float*)d_in[8];
    const float* kb    = (const float*)d_in[9];
    const float* vw    = (const float*)d_in[10];
    const float* vb    = (const float*)d_in[11];
    const float* beta  = (const float*)d_in[12];
    const float* A_log = (const float*)d_in[13];
    float* out = (float*)d_out;

    char* wsb = (char*)d_ws;
    const size_t WT  = (size_t)DIM_ * DIM_ * 2;
    const size_t SZ  = (size_t)B_ * T_ * DIM_;
    const size_t SZH = SZ * 2;

    _Float16* wtq = (_Float16*)(wsb + 0 * WT);    // wtq..wtg contiguous = Bt[8192][2048]
    _Float16* wto = (_Float16*)(wsb + 4 * WT);
    char* pbase = wsb + 5 * WT;
    _Float16* pq = (_Float16*)(pbase + 0 * SZH);  // raw q projection (live to r3)
    _Float16* pk = (_Float16*)(pbase + 1 * SZH);  // raw k projection (dead after r1)
    _Float16* pv = (_Float16*)(pbase + 2 * SZH);  // raw v projection (dead after r1)
    _Float16* xh = (_Float16*)(pbase + 3 * SZH);  // dead after proj GEMM
    _Float16* pg = (_Float16*)(pbase + 4 * SZH);  // live to r3
    _Float16* U    = (_Float16*)(pbase + 5 * SZH);  // 32 MB (slots 5-6)
    _Float16* Sst  = (_Float16*)(pbase + 7 * SZH);  // 32 MB (slots 7-8)
    _Float16* kh   = xh;                            // conv'd k (xh dead)
    _Float16* vh   = (_Float16*)(pbase + 9 * SZH);  // conv'd v (new slot)
    _Float16* gated = U;                            // U dead after r2

    // cvt + 5 weight transposes in one launch (vectorized)
    prep<<<dim3(32, 32, 6), 256, 0, stream>>>(Wq, Wk, Wv, Wg, Wo, wtq, x, xh);

    // fused projections: M=4096, N=8192 (q|k|v|g): 16x32 = 512 tiles of 256^2
    gemm8ph<256><<<512, 512, 0, stream>>>(xh, wtq, pq, pk, pv, pg,
                                          DIM_, 32, 64);

    r1_kernel<<<B_ * H_ * 32, 256, 0, stream>>>(pk, pv, kw, kb, vw, vb,
                                                A_log, beta, U, kh, vh);
    r2_kernel<<<512, 128, 0, stream>>>(U, Sst, A_log);
    r3_kernel<<<B_ * H_ * 32, 256, 0, stream>>>(pq, kh, vh, Sst, pg,
                                                qw, qb, A_log, beta, gated);

    // out = gated @ Wo : M=4096, N=2048 -> 16x16 = 256 tiles of 256x128
    gemmp<256, float><<<256, 512, 0, stream>>>(gated, wto, out, out, out, out,
                                               DIM_, 16, 32);
}

// Round 19
// 319.593 us; speedup vs baseline: 1.4490x; 1.0016x over previous
//
#include <hip/hip_runtime.h>
#include <math.h>

#define B_   2
#define T_   2048
#define DIM_ 2048
#define H_   16

typedef __attribute__((ext_vector_type(8))) _Float16 half8;
typedef __attribute__((ext_vector_type(4))) float f32x4;

__device__ __forceinline__ float sigmoidf_(float x) { return 1.0f / (1.0f + __expf(-x)); }

__device__ __forceinline__ void gload16(const _Float16* g, _Float16* l) {
    __builtin_amdgcn_global_load_lds((const __attribute__((address_space(1))) void*)g,
                                     (__attribute__((address_space(3))) void*)l, 16, 0, 0);
}

#define VMW(n) asm volatile("s_waitcnt vmcnt(" #n ")" ::: "memory")

// Swizzled transpose-LDS addressing for [row][72] f16 tiles holding [row][s].
__device__ __forceinline__ int tsw(int row, int s) {
    return row * 72 + ((((s >> 3) ^ ((row >> 3) & 7)) << 3) | (s & 7));
}
__device__ __forceinline__ int tswb(int row, int sb) {
    return row * 72 + (((sb ^ ((row >> 3) & 7)) << 3));
}

// XCD-aware block remap: partition the (16 x nx) grid into 8 square-ish
// regions of 8 rows x nx/4 cols (rband = xcd>>2, cband = xcd&3), row-fastest
// within a region. Per-XCD working set = 8 A-panels + nx/4 B-panels, cutting
// L2-missed refetch vs the 2-row strip (r18: FETCH 270->147 MB; this ~2x more).
__device__ __forceinline__ void xcd_rc(int bid, int nx, int cpx, int* row, int* col) {
    int x = bid & 7, L = bid >> 3;
    *row = ((x >> 2) << 3) + (L & 7);
    *col = (x & 3) * (nx >> 2) + (L >> 3);
    (void)cpx;
}

// Depthwise causal conv K=4, 8 channels, fp32 math.
__device__ __forceinline__ void conv8(const _Float16* __restrict__ src,
                                      const float* __restrict__ w,
                                      const float* __restrict__ bias,
                                      size_t rb, int t, int ch, float* acc)
{
    float4 w4[8];
#pragma unroll
    for (int u = 0; u < 8; ++u) {
        w4[u] = *(const float4*)(w + (ch + u) * 4);
        acc[u] = bias[ch + u];
    }
#pragma unroll
    for (int j = 0; j < 4; ++j) {
        if (t - 3 + j >= 0) {
            half8 xv = *(const half8*)(src + rb + (ptrdiff_t)(j - 3) * DIM_);
#pragma unroll
            for (int u = 0; u < 8; ++u)
                acc[u] += (float)xv[u] * ((const float*)&w4[u])[j];
        }
    }
}

// ---------------------------------------------------------------------------
// prep: z<5 -> weight transpose W[K][N] f32 -> Wt[N][K] f16 (vectorized);
//       z==5 -> x f32->f16 cvt.
// ---------------------------------------------------------------------------
__global__ __launch_bounds__(256) void prep(const float* __restrict__ W0,
                                            const float* __restrict__ W1,
                                            const float* __restrict__ W2,
                                            const float* __restrict__ W3,
                                            const float* __restrict__ W4,
                                            _Float16* __restrict__ wbase,
                                            const float* __restrict__ x,
                                            _Float16* __restrict__ xh)
{
    const int z = blockIdx.z;
    if (z == 5) {
        size_t blk = ((size_t)blockIdx.y * 32 + blockIdx.x) * 8192;
#pragma unroll
        for (int j = 0; j < 4; ++j) {
            size_t i = blk + (size_t)j * 2048 + (size_t)threadIdx.x * 8;
            float4 a = *(const float4*)(x + i);
            float4 b = *(const float4*)(x + i + 4);
            half8 h;
            h[0] = (_Float16)a.x; h[1] = (_Float16)a.y; h[2] = (_Float16)a.z; h[3] = (_Float16)a.w;
            h[4] = (_Float16)b.x; h[5] = (_Float16)b.y; h[6] = (_Float16)b.z; h[7] = (_Float16)b.w;
            *(half8*)(xh + i) = h;
        }
        return;
    }
    __shared__ float t[64 * 65];
    const float* W = z == 0 ? W0 : z == 1 ? W1 : z == 2 ? W2 : z == 3 ? W3 : W4;
    _Float16* Wt = wbase + (size_t)z * DIM_ * DIM_;
    const int n0 = blockIdx.x * 64, k0 = blockIdx.y * 64;
#pragma unroll
    for (int rep = 0; rep < 4; ++rep) {
        int row = rep * 16 + (threadIdx.x >> 4);
        int qc = threadIdx.x & 15;
        float4 v = *(const float4*)(W + (size_t)(k0 + row) * DIM_ + n0 + qc * 4);
        t[row * 65 + qc * 4 + 0] = v.x;
        t[row * 65 + qc * 4 + 1] = v.y;
        t[row * 65 + qc * 4 + 2] = v.z;
        t[row * 65 + qc * 4 + 3] = v.w;
    }
    __syncthreads();
#pragma unroll
    for (int rep = 0; rep < 2; ++rep) {
        int r = rep * 32 + (threadIdx.x >> 3);
        int q = threadIdx.x & 7;
        half8 o;
#pragma unroll
        for (int j = 0; j < 8; ++j)
            o[j] = (_Float16)t[(q * 8 + j) * 65 + r];
        *(half8*)(Wt + (size_t)(n0 + r) * DIM_ + k0 + q * 8) = o;
    }
}

// ---------------------------------------------------------------------------
// 8-phase pipelined MFMA GEMM (measured-best on proj): 256x256 tile, BK=64,
// 2 K-tiles/iter, 8 waves (2M x 4N), counted vmcnt(4), 3-bit XOR swizzle.
// Epilogue: two-pass LDS bounce -> coalesced half8 stores.
// ---------------------------------------------------------------------------
template <int BM>
__global__ __launch_bounds__(512, 1) void gemm8ph(const _Float16* __restrict__ A,
                                                  const _Float16* __restrict__ Bt,
                                                  _Float16* __restrict__ C0, _Float16* __restrict__ C1,
                                                  _Float16* __restrict__ C2, _Float16* __restrict__ C3,
                                                  int K, int nx, int cpx)
{
    constexpr int MF  = BM / 32;
    constexpr int AQ  = MF / 4;
    constexpr int ASZ = BM * 64;
    constexpr int DSZ = (BM + 256) * 64;
    __shared__ _Float16 lds[2 * DSZ];

    const int tid = threadIdx.x;
    const int lane = tid & 63, w = tid >> 6;
    const int wr = w >> 2, wc = w & 3;
    const int l15 = lane & 15, l16 = lane >> 4;

    int brow, bcol;
    xcd_rc(blockIdx.x, nx, cpx, &brow, &bcol);
    const int bm = brow * BM, bn = bcol * 256;

    const int r0 = tid >> 3;
    const int c0 = ((tid & 7) ^ (r0 & 7)) * 8;
    const _Float16* Ab = A + (size_t)(bm + r0) * K + c0;
    const _Float16* Bb = Bt + (size_t)(bn + r0) * K + c0;

#define STAGE_A(d, kt) do { _Pragma("unroll")                                    \
    for (int u = 0; u < BM / 64; ++u)                                            \
        gload16(Ab + (size_t)(u * 64) * K + (size_t)(kt) * 64,                   \
                lds + (d) * DSZ + u * 4096 + tid * 8); } while (0)
#define STAGE_B(d, h, kt) do {                                                   \
    gload16(Bb + (size_t)((h) * 128) * K + (size_t)(kt) * 64,                    \
            lds + (d) * DSZ + ASZ + (h) * 8192 + tid * 8);                       \
    gload16(Bb + (size_t)((h) * 128 + 64) * K + (size_t)(kt) * 64,               \
            lds + (d) * DSZ + ASZ + (h) * 8192 + 4096 + tid * 8); } while (0)

    int aoff[MF][2], boff[4][2];
#pragma unroll
    for (int m = 0; m < MF; ++m) {
        int R = wr * (BM / 2) + m * 16 + l15;
#pragma unroll
        for (int ks = 0; ks < 2; ++ks)
            aoff[m][ks] = R * 64 + (((ks * 4 + l16) ^ (R & 7)) * 8);
    }
#pragma unroll
    for (int n = 0; n < 4; ++n) {
        int R = wc * 64 + n * 16 + l15;
#pragma unroll
        for (int ks = 0; ks < 2; ++ks)
            boff[n][ks] = ASZ + R * 64 + (((ks * 4 + l16) ^ (R & 7)) * 8);
    }

    f32x4 acc[MF][4] = {};
    half8 bfr[4][2];
    const int nj = K >> 7;

    STAGE_A(0, 0);
    STAGE_B(0, 0, 0); STAGE_B(0, 1, 0);
    STAGE_B(1, 0, 1); STAGE_B(1, 1, 1);
    VMW(4);
    __builtin_amdgcn_s_barrier();
    __builtin_amdgcn_sched_barrier(0);

#define PH(TT, Q, STAGECODE, VMCODE) do {                                        \
    const int dB_ = (TT) * DSZ;                                                  \
    half8 af_[AQ][2];                                                            \
    if ((Q) == 0) {                                                              \
        _Pragma("unroll") for (int n_ = 0; n_ < 4; ++n_)                         \
        _Pragma("unroll") for (int ks_ = 0; ks_ < 2; ++ks_)                      \
            bfr[n_][ks_] = *(const half8*)(lds + dB_ + boff[n_][ks_]);           \
    }                                                                            \
    _Pragma("unroll") for (int a_ = 0; a_ < AQ; ++a_)                            \
    _Pragma("unroll") for (int ks_ = 0; ks_ < 2; ++ks_)                          \
        af_[a_][ks_] = *(const half8*)(lds + dB_ + aoff[(Q) * AQ + a_][ks_]);    \
    STAGECODE;                                                                   \
    __builtin_amdgcn_s_barrier();                                                \
    asm volatile("s_waitcnt lgkmcnt(0)" ::: "memory");                           \
    __builtin_amdgcn_sched_barrier(0);                                           \
    __builtin_amdgcn_s_setprio(1);                                               \
    _Pragma("unroll") for (int ks_ = 0; ks_ < 2; ++ks_)                          \
    _Pragma("unroll") for (int a_ = 0; a_ < AQ; ++a_)                            \
    _Pragma("unroll") for (int n_ = 0; n_ < 4; ++n_)                             \
        acc[(Q) * AQ + a_][n_] = __builtin_amdgcn_mfma_f32_16x16x32_f16(         \
            af_[a_][ks_], bfr[n_][ks_], acc[(Q) * AQ + a_][n_], 0, 0, 0);        \
    __builtin_amdgcn_s_setprio(0);                                               \
    __builtin_amdgcn_sched_barrier(0);                                           \
    VMCODE;                                                                      \
    __builtin_amdgcn_s_barrier();                                                \
} while (0)

    for (int j = 0; j < nj; ++j) {
        const bool pf = (j + 1 < nj);
        const int t1 = 2 * j + 1, tn0 = 2 * j + 2, tn1 = 2 * j + 3;
        PH(0, 0, { STAGE_A(1, t1); }, {});
        PH(0, 1, { if (pf) STAGE_B(0, 0, tn0); }, {});
        PH(0, 2, { if (pf) STAGE_B(0, 1, tn0); }, {});
        PH(0, 3, {}, { if (pf) { VMW(4); } else { VMW(0); } });
        PH(1, 0, { if (pf) STAGE_A(0, tn0); }, {});
        PH(1, 1, {}, {});
        PH(1, 2, { if (pf) STAGE_B(1, 0, tn1); }, {});
        PH(1, 3, { if (pf) STAGE_B(1, 1, tn1); }, { if (pf) VMW(4); });
    }
#undef PH
#undef STAGE_A
#undef STAGE_B

    const int sel = bn >> 11;
    _Float16* __restrict__ C = sel == 0 ? C0 : sel == 1 ? C1 : sel == 2 ? C2 : C3;
    const int ccol0 = bn & 2047;
    _Float16* bb = lds;
#pragma unroll
    for (int p = 0; p < 2; ++p) {
        if (p) __syncthreads();
        if (wr == p) {
#pragma unroll
            for (int m = 0; m < MF; ++m)
#pragma unroll
                for (int n = 0; n < 4; ++n)
#pragma unroll
                    for (int r = 0; r < 4; ++r)
                        bb[(m * 16 + l16 * 4 + r) * 264 + wc * 64 + n * 16 + l15] =
                            (_Float16)acc[m][n][r];
        }
        __syncthreads();
#pragma unroll
        for (int rep = 0; rep < 8; ++rep) {
            int u = rep * 512 + tid;
            int i = u >> 5, q = u & 31;
            *(half8*)(C + (size_t)(bm + p * 128 + i) * 2048 + ccol0 + q * 8) =
                *(const half8*)(bb + i * 264 + q * 8);
        }
    }
}

// ---------------------------------------------------------------------------
// Occupancy-2 pipelined GEMM for the Wo matmul: 256x128, BK=32, 8 waves,
// 3 LDS buffers, counted vmcnt, verified swizzle, two-pass f32 bounce.
// ---------------------------------------------------------------------------
template <int BM, typename OT>
__global__ __launch_bounds__(512, 4) void gemmp(const _Float16* __restrict__ A,
                                                const _Float16* __restrict__ Bt,
                                                OT* __restrict__ C0, OT* __restrict__ C1,
                                                OT* __restrict__ C2, OT* __restrict__ C3,
                                                int K, int nx, int cpx)
{
    static_assert(BM == 256, "two-pass epilogue assumes BM=256");
    constexpr int BN   = 128;
    constexpr int LPT  = (BM + BN) / 128;
    constexpr int WR   = BM / 4;
    constexpr int MF   = WR / 16;
    constexpr int ASZ  = BM * 32;
    constexpr int DSZ  = (BM + BN) * 32;
    __shared__ alignas(16) char ldsraw[3 * DSZ * 2];
    _Float16* lds = reinterpret_cast<_Float16*>(ldsraw);

    const int tid = threadIdx.x;
    const int lane = tid & 63, w = tid >> 6;
    const int wr = w >> 1, wc = w & 1;
    const int l15 = lane & 15, l16 = lane >> 4;

    int brow, bcol;
    xcd_rc(blockIdx.x, nx, cpx, &brow, &bcol);
    const int bm = brow * BM, bn = bcol * BN;

    const _Float16* src[LPT];
    int ldst[LPT];
#pragma unroll
    for (int ld = 0; ld < LPT; ++ld) {
        int F = ld * 512 + tid;
        int R = F >> 2;
        int sc = (F & 3) ^ (((R >> 3) & 1) << 1);
        src[ld] = (R < BM) ? A + (size_t)(bm + R) * K + sc * 8
                           : Bt + (size_t)(bn + R - BM) * K + sc * 8;
        ldst[ld] = F * 8;
    }

    int aoff[MF], boff[4];
#pragma unroll
    for (int m = 0; m < MF; ++m) {
        int R = wr * WR + m * 16 + l15;
        aoff[m] = R * 32 + ((l16 ^ (((R >> 3) & 1) << 1)) * 8);
    }
#pragma unroll
    for (int n = 0; n < 4; ++n) {
        int R = wc * 64 + n * 16 + l15;
        boff[n] = ASZ + R * 32 + ((l16 ^ (((R >> 3) & 1) << 1)) * 8);
    }

    f32x4 acc[MF][4] = {};
    const int nt = K >> 5;

#define STAGE(kt, buf) do { _Pragma("unroll")                                  \
    for (int ld_ = 0; ld_ < LPT; ++ld_)                                        \
        gload16(src[ld_] + (size_t)(kt) * 32, lds + (buf) * DSZ + ldst[ld_]);  \
    } while (0)

    STAGE(0, 0);
    STAGE(1, 1);
    VMW(3);
    __builtin_amdgcn_s_barrier();
    __builtin_amdgcn_sched_barrier(0);

    int cb = 0, nb = 2;
    for (int t = 0; t < nt; ++t) {
        const _Float16* L = lds + cb * DSZ;
        half8 af[MF], bf[4];
#pragma unroll
        for (int m = 0; m < MF; ++m) af[m] = *(const half8*)(L + aoff[m]);
#pragma unroll
        for (int n = 0; n < 4; ++n) bf[n] = *(const half8*)(L + boff[n]);

        const bool pf = (t + 2 < nt);
        if (pf) STAGE(t + 2, nb);

        asm volatile("s_waitcnt lgkmcnt(0)" ::: "memory");
        __builtin_amdgcn_sched_barrier(0);
        __builtin_amdgcn_s_setprio(1);
#pragma unroll
        for (int m = 0; m < MF; ++m)
#pragma unroll
            for (int n = 0; n < 4; ++n)
                acc[m][n] = __builtin_amdgcn_mfma_f32_16x16x32_f16(af[m], bf[n], acc[m][n], 0, 0, 0);
        __builtin_amdgcn_s_setprio(0);
        __builtin_amdgcn_sched_barrier(0);

        if (pf) VMW(3);
        else    VMW(0);
        __builtin_amdgcn_s_barrier();
        __builtin_amdgcn_sched_barrier(0);

        cb = (cb == 2) ? 0 : cb + 1;
        nb = (nb == 2) ? 0 : nb + 1;
    }
#undef STAGE

    const int sel = bn >> 11;
    OT* __restrict__ C = sel == 0 ? C0 : sel == 1 ? C1 : sel == 2 ? C2 : C3;
    const int ccol0 = bn & 2047;
    constexpr int VE = 16 / sizeof(OT);
    constexpr int CPR = 128 / VE;
    constexpr int BW = 128 + VE;
    OT* bb = reinterpret_cast<OT*>(ldsraw);
#pragma unroll
    for (int p = 0; p < 2; ++p) {
        if (p) __syncthreads();
        if ((wr >> 1) == p) {
            const int rb = (wr & 1) * 64;
#pragma unroll
            for (int m = 0; m < MF; ++m)
#pragma unroll
                for (int n = 0; n < 4; ++n)
#pragma unroll
                    for (int r = 0; r < 4; ++r)
                        bb[(rb + m * 16 + l16 * 4 + r) * BW + wc * 64 + n * 16 + l15] =
                            (OT)acc[m][n][r];
        }
        __syncthreads();
#pragma unroll
        for (int rep = 0; rep < (128 * CPR) / 512; ++rep) {
            int u = rep * 512 + tid;
            int i = u / CPR, q = u % CPR;
            if constexpr (sizeof(OT) == 2)
                *reinterpret_cast<half8*>(C + (size_t)(bm + p * 128 + i) * 2048 + ccol0 + q * VE) =
                    *reinterpret_cast<const half8*>(bb + i * BW + q * VE);
            else
                *reinterpret_cast<float4*>(C + (size_t)(bm + p * 128 + i) * 2048 + ccol0 + q * VE) =
                    *reinterpret_cast<const float4*>(bb + i * BW + q * VE);
        }
    }
}

// ---------------------------------------------------------------------------
// R1 (conv fused): per (bh, chunk) U_c = sum_s bet*decay^(63-s) v_s k_s^T.
// Also EXPORTS conv'd kh (normalized) and vh so r3 need not recompute them.
// ---------------------------------------------------------------------------
__global__ __launch_bounds__(256) void r1_kernel(const _Float16* __restrict__ pk,
                                                 const _Float16* __restrict__ pv,
                                                 const float* __restrict__ kw,
                                                 const float* __restrict__ kb,
                                                 const float* __restrict__ vw,
                                                 const float* __restrict__ vb,
                                                 const float* __restrict__ A_log,
                                                 const float* __restrict__ beta,
                                                 _Float16* __restrict__ U,
                                                 _Float16* __restrict__ kh,
                                                 _Float16* __restrict__ vh)
{
    const int c = blockIdx.x & 31, bh = blockIdx.x >> 5;
    const int h = bh & 15, b = bh >> 4;
    const float decay = sigmoidf_(A_log[h]);
    const float bet = sigmoidf_(beta[h]);
    const float ld = logf(decay);

    __shared__ _Float16 sm[2 * 128 * 72];
    _Float16* kt = sm;
    _Float16* vt = sm + 128 * 72;

    const int tid = threadIdx.x;

#pragma unroll
    for (int rep = 0; rep < 4; ++rep) {
        int s = rep * 16 + (tid >> 4);
        int dq = tid & 15;
        int t = c * 64 + s;
        int ch = h * 128 + dq * 8;
        size_t rb = ((size_t)(b * T_ + t)) * DIM_ + ch;
        float ka[8], va[8];
        conv8(pk, kw, kb, rb, t, ch, ka);
        conv8(pv, vw, vb, rb, t, ch, va);
        float ss = 0.0f;
#pragma unroll
        for (int u = 0; u < 8; ++u) {
            ka[u] = ka[u] * sigmoidf_(ka[u]);
            ss += ka[u] * ka[u];
        }
        ss += __shfl_xor(ss, 1);
        ss += __shfl_xor(ss, 2);
        ss += __shfl_xor(ss, 4);
        ss += __shfl_xor(ss, 8);
        float sc = 1.0f / fmaxf(sqrtf(ss), 1e-12f);
        float vsc = bet * __expf(ld * (float)(63 - s));
        half8 k8, v8;
#pragma unroll
        for (int u = 0; u < 8; ++u) {
            k8[u] = (_Float16)(ka[u] * sc);
            v8[u] = (_Float16)va[u];
            kt[tsw(dq * 8 + u, s)] = k8[u];
            vt[tsw(dq * 8 + u, s)] = (_Float16)(vsc * va[u]);
        }
        *(half8*)(kh + rb) = k8;   // export for r3 (identical rounding path)
        *(half8*)(vh + rb) = v8;
    }
    __syncthreads();

    const int lane = tid & 63, w = tid >> 6;
    const int l15 = lane & 15, l16 = lane >> 4;
    f32x4 acc[2][8] = {};
#pragma unroll
    for (int ks = 0; ks < 2; ++ks) {
        half8 a0 = *(const half8*)(vt + tswb(w * 32 + l15,      ks * 4 + l16));
        half8 a1 = *(const half8*)(vt + tswb(w * 32 + 16 + l15, ks * 4 + l16));
#pragma unroll
        for (int fj = 0; fj < 8; ++fj) {
            half8 bf = *(const half8*)(kt + tswb(fj * 16 + l15, ks * 4 + l16));
            acc[0][fj] = __builtin_amdgcn_mfma_f32_16x16x32_f16(a0, bf, acc[0][fj], 0, 0, 0);
            acc[1][fj] = __builtin_amdgcn_mfma_f32_16x16x32_f16(a1, bf, acc[1][fj], 0, 0, 0);
        }
    }
    __syncthreads();

    _Float16* buf = sm;
#pragma unroll
    for (int fi = 0; fi < 2; ++fi)
#pragma unroll
        for (int fj = 0; fj < 8; ++fj)
#pragma unroll
            for (int r = 0; r < 4; ++r)
                buf[(w * 32 + fi * 16 + l16 * 4 + r) * 136 + fj * 16 + l15] =
                    (_Float16)acc[fi][fj][r];
    __syncthreads();

    _Float16* Ub = U + (((size_t)blockIdx.x) << 14);
#pragma unroll
    for (int rep = 0; rep < 8; ++rep) {
        int u = rep * 256 + tid;
        int i = u >> 4, jq = u & 15;
        *(half8*)(Ub + i * 128 + jq * 8) = *(const half8*)(buf + i * 136 + jq * 8);
    }
}

// ---------------------------------------------------------------------------
// R2: chunk-boundary state scan; 512 blocks x 128 threads, STATIC 2-deep
// prefetch (named n0/n1). Output Sst in FRAGMENT-ORDERED layout.
// ---------------------------------------------------------------------------
__global__ __launch_bounds__(128) void r2_kernel(const _Float16* __restrict__ U,
                                                 _Float16* __restrict__ S,
                                                 const float* __restrict__ A_log)
{
    const int blk = blockIdx.x;
    const int bh = blk >> 4, part = blk & 15, h = bh & 15;
    const float decay = sigmoidf_(A_log[h]);
    const float d64 = __expf(64.0f * logf(decay));
    const int tid = threadIdx.x;
    const size_t base = ((size_t)bh << 19) + (size_t)part * 1024 + (size_t)tid * 8;
    const half8* Up = (const half8*)(U + base);

    const int v  = part * 8 + (tid >> 4);
    const int d0 = (tid & 15) * 8;
    const int nf = v >> 4, l15 = v & 15;
    const int kd = d0 >> 5, l16 = (d0 >> 3) & 3;
    half8* Sp = (half8*)(S + ((size_t)bh << 19) +
                         (size_t)(((nf * 4 + kd) * 64) + l16 * 16 + l15) * 8);

    float st[8] = {0, 0, 0, 0, 0, 0, 0, 0};
    half8 n0 = Up[0];
    half8 n1 = Up[2048];
    for (int c = 0; c < 32; ++c) {
        half8 cur = n0;
        n0 = n1;
        if (c + 2 < 32) n1 = Up[(size_t)(c + 2) * 2048];
        half8 so;
#pragma unroll
        for (int i = 0; i < 8; ++i) {
            so[i] = (_Float16)st[i];
            st[i] = d64 * st[i] + (float)cur[i];
        }
        Sp[(size_t)c * 2048] = so;
    }
}

// ---------------------------------------------------------------------------
// R3: out = mask(QK^T)V + rowscale(Q S^T), gated. Reads pre-conv'd kh/vh
// from r1; S fragments read coalesced from r2's fragment-ordered layout.
// ---------------------------------------------------------------------------
__global__ __launch_bounds__(256) void r3_kernel(const _Float16* __restrict__ pq,
                                                 const _Float16* __restrict__ kh,
                                                 const _Float16* __restrict__ vh,
                                                 const _Float16* __restrict__ S,
                                                 const _Float16* __restrict__ pg,
                                                 const float* __restrict__ qw,
                                                 const float* __restrict__ qb,
                                                 const float* __restrict__ A_log,
                                                 const float* __restrict__ beta,
                                                 _Float16* __restrict__ gated)
{
    const int c = blockIdx.x & 31, bh = blockIdx.x >> 5;
    const int h = bh & 15, b = bh >> 4;
    const float decay = sigmoidf_(A_log[h]);
    const float bet = sigmoidf_(beta[h]);
    const float ld = logf(decay);

    __shared__ _Float16 vt[128 * 72];       // [n][s] swizzled (tsw)
    __shared__ _Float16 kbuf[64 * 136];     // k; reused as out bounce
    __shared__ _Float16 qps[64 * 136];      // conv'd q; reused as masked-P
    __shared__ float e1[65];

    const int tid = threadIdx.x;
    if (tid < 65) e1[tid] = __expf(ld * (float)tid);

#pragma unroll
    for (int rep = 0; rep < 4; ++rep) {
        int s = rep * 16 + (tid >> 4);
        int nq = tid & 15;
        int t = c * 64 + s;
        int ch = h * 128 + nq * 8;
        size_t rb = ((size_t)(b * T_ + t)) * DIM_ + ch;
        half8 k8 = *(const half8*)(kh + rb);
        half8 v8 = *(const half8*)(vh + rb);
        float qa[8];
        conv8(pq, qw, qb, rb, t, ch, qa);
        half8 q8;
#pragma unroll
        for (int u = 0; u < 8; ++u) {
            float q = qa[u];
            q8[u] = (_Float16)(q * sigmoidf_(q));
            vt[tsw(nq * 8 + u, s)] = v8[u];
        }
        *(half8*)(kbuf + s * 136 + ((nq ^ (s & 7)) * 8)) = k8;
        *(half8*)(qps + s * 136 + ((nq ^ (s & 7)) * 8)) = q8;
    }
    __syncthreads();

    const int lane = tid & 63, w = tid >> 6;
    const int l15 = lane & 15, l16 = lane >> 4;
    const int qr = w * 16 + l15;

    half8 af[4];
#pragma unroll
    for (int kd = 0; kd < 4; ++kd)
        af[kd] = *(const half8*)(qps + qr * 136 + (((kd * 4 + l16) ^ (qr & 7)) * 8));
    __syncthreads();   // all waves hold Q in regs before qps is overwritten

    f32x4 pacc[4] = {};
#pragma unroll
    for (int sf = 0; sf < 4; ++sf) {
        int s = sf * 16 + l15;
#pragma unroll
        for (int kd = 0; kd < 4; ++kd) {
            half8 bf = *(const half8*)(kbuf + s * 136 + (((kd * 4 + l16) ^ (s & 7)) * 8));
            pacc[sf] = __builtin_amdgcn_mfma_f32_16x16x32_f16(af[kd], bf, pacc[sf], 0, 0, 0);
        }
    }
#pragma unroll
    for (int sf = 0; sf < 4; ++sf)
#pragma unroll
        for (int r = 0; r < 4; ++r) {
            int tl = w * 16 + l16 * 4 + r;
            int s = sf * 16 + l15;
            float f = (s <= tl) ? bet * e1[tl - s] : 0.0f;
            qps[tl * 72 + s] = (_Float16)(pacc[sf][r] * f);   // ps[tl][s]
        }
    __syncthreads();

    half8 pf[2];
#pragma unroll
    for (int ks = 0; ks < 2; ++ks)
        pf[ks] = *(const half8*)(qps + (w * 16 + l15) * 72 + ks * 32 + l16 * 8);

    f32x4 acc1[8] = {};
    f32x4 acc2[8] = {};
    const _Float16* Sb = S + (((size_t)blockIdx.x) << 14);
#pragma unroll
    for (int nf = 0; nf < 8; ++nf) {
#pragma unroll
        for (int kd = 0; kd < 4; ++kd) {
            half8 bf = *(const half8*)(Sb + (size_t)((nf * 4 + kd) * 64 + lane) * 8);
            acc1[nf] = __builtin_amdgcn_mfma_f32_16x16x32_f16(af[kd], bf, acc1[nf], 0, 0, 0);
        }
#pragma unroll
        for (int ks = 0; ks < 2; ++ks) {
            half8 bf = *(const half8*)(vt + tswb(nf * 16 + l15, ks * 4 + l16));
            acc2[nf] = __builtin_amdgcn_mfma_f32_16x16x32_f16(pf[ks], bf, acc2[nf], 0, 0, 0);
        }
    }
#pragma unroll
    for (int nf = 0; nf < 8; ++nf)
#pragma unroll
        for (int r = 0; r < 4; ++r) {
            int tl = w * 16 + l16 * 4 + r;
            float o = acc2[nf][r] + e1[tl + 1] * acc1[nf][r];
            kbuf[tl * 136 + nf * 16 + l15] = (_Float16)o;
        }
    __syncthreads();

#pragma unroll
    for (int rep = 0; rep < 4; ++rep) {
        int u = rep * 256 + tid;
        int tl = u >> 4, jq = u & 15;
        size_t row = (size_t)(b * T_ + c * 64 + tl);
        half8 o8 = *(const half8*)(kbuf + tl * 136 + jq * 8);
        half8 g8 = *(const half8*)(pg + row * DIM_ + h * 128 + jq * 8);
        half8 r8;
#pragma unroll
        for (int j = 0; j < 8; ++j)
            r8[j] = (_Float16)((float)o8[j] * sigmoidf_((float)g8[j]));
        *(half8*)(gated + row * DIM_ + h * 128 + jq * 8) = r8;
    }
}

// ---------------------------------------------------------------------------
extern "C" void kernel_launch(void* const* d_in, const int* in_sizes, int n_in,
                              void* d_out, int out_size, void* d_ws, size_t ws_size,
                              hipStream_t stream)
{
    const float* x     = (const float*)d_in[0];
    const float* Wq    = (const float*)d_in[1];
    const float* Wk    = (const float*)d_in[2];
    const float* Wv    = (const float*)d_in[3];
    const float* Wo    = (const float*)d_in[4];
    const float* Wg    = (const float*)d_in[5];
    const float* qw    = (const float*)d_in[6];
    const float* qb    = (const float*)d_in[7];
    const float* kw    = (const float*)d_in[8];
    const float* kb    = (const float*)d_in[9];
    const float* vw    = (const float*)d_in[10];
    const float* vb    = (const float*)d_in[11];
    const float* beta  = (const float*)d_in[12];
    const float* A_log = (const float*)d_in[13];
    float* out = (float*)d_out;

    char* wsb = (char*)d_ws;
    const size_t WT  = (size_t)DIM_ * DIM_ * 2;
    const size_t SZ  = (size_t)B_ * T_ * DIM_;
    const size_t SZH = SZ * 2;

    _Float16* wtq = (_Float16*)(wsb + 0 * WT);    // wtq..wtg contiguous = Bt[8192][2048]
    _Float16* wto = (_Float16*)(wsb + 4 * WT);
    char* pbase = wsb + 5 * WT;
    _Float16* pq = (_Float16*)(pbase + 0 * SZH);  // raw q projection (live to r3)
    _Float16* pk = (_Float16*)(pbase + 1 * SZH);  // raw k projection (dead after r1)
    _Float16* pv = (_Float16*)(pbase + 2 * SZH);  // raw v projection (dead after r1)
    _Float16* xh = (_Float16*)(pbase + 3 * SZH);  // dead after proj GEMM
    _Float16* pg = (_Float16*)(pbase + 4 * SZH);  // live to r3
    _Float16* U    = (_Float16*)(pbase + 5 * SZH);  // 32 MB (slots 5-6)
    _Float16* Sst  = (_Float16*)(pbase + 7 * SZH);  // 32 MB (slots 7-8)
    _Float16* kh   = xh;                            // conv'd k (xh dead)
    _Float16* vh   = (_Float16*)(pbase + 9 * SZH);  // conv'd v (new slot)
    _Float16* gated = U;                            // U dead after r2

    // cvt + 5 weight transposes in one launch (vectorized)
    prep<<<dim3(32, 32, 6), 256, 0, stream>>>(Wq, Wk, Wv, Wg, Wo, wtq, x, xh);

    // fused projections: M=4096, N=8192 (q|k|v|g): 16x32 = 512 tiles of 256^2
    gemm8ph<256><<<512, 512, 0, stream>>>(xh, wtq, pq, pk, pv, pg,
                                          DIM_, 32, 64);

    r1_kernel<<<B_ * H_ * 32, 256, 0, stream>>>(pk, pv, kw, kb, vw, vb,
                                                A_log, beta, U, kh, vh);
    r2_kernel<<<512, 128, 0, stream>>>(U, Sst, A_log);
    r3_kernel<<<B_ * H_ * 32, 256, 0, stream>>>(pq, kh, vh, Sst, pg,
                                                qw, qb, A_log, beta, gated);

    // out = gated @ Wo : M=4096, N=2048 -> 16x16 = 256 tiles of 256x128
    gemmp<256, float><<<256, 512, 0, stream>>>(gated, wto, out, out, out, out,
                                               DIM_, 16, 32);
}